// Round 3
// baseline (1495.298 us; speedup 1.0000x reference)
//
#include <hip/hip_runtime.h>
#include <stdint.h>

#define DIM   1024
#define HID   2816
#define NEXP  2
#define NTOK  32768
#define RMS_EPS 1e-5f
#define NK1 (DIM / 64)   // 16 K-tiles for GEMM1
#define NK2 (HID / 64)   // 44 K-tiles for GEMM2

// grid geometry for XCD swizzle (must match launch)
#define NMT   (NTOK / 256)          // 128 mT blocks launched per expert
#define NWG1  ((HID / 128) * NMT)   // 2816 per expert (22 nT)
#define NWG2  ((DIM / 256) * NMT)   // 512 per expert (4 nT)

typedef unsigned short u16;
typedef unsigned int   u32;
typedef __bf16 bf16_t;
typedef bf16_t bf16x8 __attribute__((ext_vector_type(8)));
typedef float  f32x4  __attribute__((ext_vector_type(4)));

#define BAR() asm volatile("s_barrier" ::: "memory")
#define MFMA_(a,b,c) __builtin_amdgcn_mfma_f32_16x16x32_bf16(a, b, c, 0, 0, 0)

__device__ __forceinline__ u16 f2bf(float f) {
  u32 u = __float_as_uint(f);
  u += 0x7FFFu + ((u >> 16) & 1u);   // RNE
  return (u16)(u >> 16);
}

__device__ __forceinline__ void gld16(void* lds, const void* g) {
  __builtin_amdgcn_global_load_lds(
      (__attribute__((address_space(1))) void*)g,
      (__attribute__((address_space(3))) void*)lds, 16, 0, 0);
}

// ---------------- mask decoding (layout-robust) ----------------
__device__ __forceinline__ int detect_layout(const u32* mi) {
  const int lane = threadIdx.x & 63;
  bool all01 = true, allf = true;
  for (int j = 0; j < 8; ++j) {
    u32 w = mi[j * 64 + lane];
    all01 &= (w <= 1u);
    allf  &= (w == 0u || w == 0x3F800000u);
  }
  unsigned long long b01 = __ballot(all01);
  unsigned long long bfl = __ballot(allf);
  if (b01 == ~0ull) return 0;
  if (bfl == ~0ull) return 1;
  return 2;
}

__device__ __forceinline__ bool mask_at(const void* m, int layout, int e, int n) {
  if (layout == 0) return ((const u32*)m)[e * NTOK + n] != 0u;
  if (layout == 1) return ((const float*)m)[e * NTOK + n] != 0.f;
  return ((const unsigned char*)m)[e * NTOK + n] != 0;
}

__device__ __forceinline__ int label_of(const void* m, int layout, int n) {
  for (int e = 0; e < NEXP; ++e)
    if (mask_at(m, layout, e, n)) return e;
  return 0;
}

__global__ void k_count(const void* __restrict__ masks, int* __restrict__ meta) {
  const int layout = detect_layout((const u32*)masks);
  const int n = blockIdx.x * blockDim.x + threadIdx.x;
  if (n < NTOK) atomicAdd(&meta[label_of(masks, layout, n)], 1);
}

__global__ void k_scan(int* __restrict__ meta) {
  if (threadIdx.x == 0) { meta[2] = 0; meta[3] = meta[0]; }
}

__global__ void k_fill(const void* __restrict__ masks, int* __restrict__ meta,
                       int* __restrict__ idx) {
  const int layout = detect_layout((const u32*)masks);
  const int n = blockIdx.x * blockDim.x + threadIdx.x;
  if (n < NTOK) {
    const int e = label_of(masks, layout, n);
    const int pos = atomicAdd(&meta[2 + e], 1);
    idx[pos] = n;
  }
}

// ---------------- f32 -> bf16 conversion ----------------
__global__ void k_cvt(const float* __restrict__ in, u16* __restrict__ out, int n4) {
  const int i = blockIdx.x * blockDim.x + threadIdx.x;
  if (i >= n4) return;
  const float4 v = ((const float4*)in)[i];
  ushort4 o;
  o.x = f2bf(v.x); o.y = f2bf(v.y); o.z = f2bf(v.z); o.w = f2bf(v.w);
  ((ushort4*)out)[i] = o;
}

// ============================================================================
// GEMM1: h = silu(X@W1^T) * (X@W3^T), gathered rows.
// 8-phase counted-vmcnt schedule. BM=256, BN=128 (dual B), BK=64,
// 8 waves (2M x 4N), 128 KiB LDS (2 dbuf).
// T1 XCD swizzle: hardware wg i -> XCD i%8; logical id (nT-band, mT-fast)
// so each XCD keeps its w1/w3 stripe L2-resident across the mT sweep.
// ============================================================================

#define G1_STAGE_A(BUF, HH, KT) {                                     \
    char* _d = (char*)&sA[BUF][(HH) * 8192] + t * 16;                 \
    gld16(_d,        ((HH) ? aptr2 : aptr0) + (size_t)(KT) * 64);     \
    gld16(_d + 8192, ((HH) ? aptr3 : aptr1) + (size_t)(KT) * 64); }

#define G1_STAGE_B(BUF, HH, KT) {                                     \
    gld16((char*)&sB1[BUF][(HH) * 4096] + t * 16,                     \
          ((HH) ? b1p1 : b1p0) + (size_t)(KT) * 64);                  \
    gld16((char*)&sB3[BUF][(HH) * 4096] + t * 16,                     \
          ((HH) ? b3p1 : b3p0) + (size_t)(KT) * 64); }

#define G1_PH(MQ, NQ, ...) {                                                   \
    if ((NQ) == 0) {                                                           \
      _Pragma("unroll") for (int mi = 0; mi < 4; ++mi) {                       \
        af0[mi] = *(const bf16x8*)&sAc[aBase + (MQ)*8192 + mi*1024 + kb0];     \
        af1[mi] = *(const bf16x8*)&sAc[aBase + (MQ)*8192 + mi*1024 + kb1];     \
      }                                                                        \
    }                                                                          \
    b1f0 = *(const bf16x8*)&sB1c[bBase + (NQ)*4096 + kb0];                     \
    b1f1 = *(const bf16x8*)&sB1c[bBase + (NQ)*4096 + kb1];                     \
    b3f0 = *(const bf16x8*)&sB3c[bBase + (NQ)*4096 + kb0];                     \
    b3f1 = *(const bf16x8*)&sB3c[bBase + (NQ)*4096 + kb1];                     \
    __VA_ARGS__                                                                \
    BAR();                                                                     \
    __builtin_amdgcn_s_setprio(1);                                             \
    _Pragma("unroll") for (int mi = 0; mi < 4; ++mi) {                         \
      acc1[MQ][NQ][mi] = MFMA_(af0[mi], b1f0, acc1[MQ][NQ][mi]);               \
      acc3[MQ][NQ][mi] = MFMA_(af0[mi], b3f0, acc3[MQ][NQ][mi]);               \
      acc1[MQ][NQ][mi] = MFMA_(af1[mi], b1f1, acc1[MQ][NQ][mi]);               \
      acc3[MQ][NQ][mi] = MFMA_(af1[mi], b3f1, acc3[MQ][NQ][mi]);               \
    }                                                                          \
    __builtin_amdgcn_s_setprio(0);                                             \
  }

__global__ __launch_bounds__(512, 2) void k_gemm1(
    const u16* __restrict__ xb, const u16* __restrict__ w1b,
    const u16* __restrict__ w3b, const int* __restrict__ meta,
    const int* __restrict__ idx, u16* __restrict__ h)
{
  const int e    = blockIdx.z;
  const int cnt  = meta[e];
  const int base = e ? meta[0] : 0;

  // T1 bijective XCD swizzle (per-z nwg = 2816, 2816 % 8 == 0)
  const int olin    = blockIdx.y * gridDim.x + blockIdx.x;
  const int logical = (olin & 7) * (NWG1 >> 3) + (olin >> 3);
  const int mT      = logical & (NMT - 1);   // fast: mT sweep within XCD band
  const int nT      = logical >> 7;          // slow: nT band per XCD
  if (mT * 256 >= cnt) return;

  __shared__ __attribute__((aligned(16))) u16 sA [2][256 * 64];
  __shared__ __attribute__((aligned(16))) u16 sB1[2][128 * 64];
  __shared__ __attribute__((aligned(16))) u16 sB3[2][128 * 64];

  const int t = threadIdx.x;
  const int srcoff = ((t & 7) ^ ((t >> 3) & 7)) * 8;   // pre-swizzled src (u16)
  const int r0 = t >> 3;

  const u16 *aptr0, *aptr1, *aptr2, *aptr3;
  {
    int rg;
    rg = mT*256 +   0 + r0; rg = rg < cnt ? rg : cnt-1; aptr0 = xb + (size_t)idx[base+rg]*DIM + srcoff;
    rg = mT*256 +  64 + r0; rg = rg < cnt ? rg : cnt-1; aptr1 = xb + (size_t)idx[base+rg]*DIM + srcoff;
    rg = mT*256 + 128 + r0; rg = rg < cnt ? rg : cnt-1; aptr2 = xb + (size_t)idx[base+rg]*DIM + srcoff;
    rg = mT*256 + 192 + r0; rg = rg < cnt ? rg : cnt-1; aptr3 = xb + (size_t)idx[base+rg]*DIM + srcoff;
  }
  const u16 *b1p0, *b1p1, *b3p0, *b3p1;
  {
    size_t o0 = ((size_t)e * HID + (size_t)nT * 128 +      r0) * DIM + srcoff;
    size_t o1 = ((size_t)e * HID + (size_t)nT * 128 + 64 + r0) * DIM + srcoff;
    b1p0 = w1b + o0; b1p1 = w1b + o1;
    b3p0 = w3b + o0; b3p1 = w3b + o1;
  }

  const int wid = t >> 6, l = t & 63;
  const int wr = wid >> 2, wc = wid & 3;
  const int l15 = l & 15, lk = l >> 4, l7 = l & 7;
  const int kb0 = ((0 + lk) ^ l7) * 8;
  const int kb1 = ((4 + lk) ^ l7) * 8;
  const int aBase = (wr * 64 + l15) * 64;
  const int bBase = (wc * 16 + l15) * 64;

  f32x4 acc1[2][2][4] = {};
  f32x4 acc3[2][2][4] = {};
  bf16x8 af0[4], af1[4], b1f0, b1f1, b3f0, b3f1;

  // prologue: tile0 full (8 loads) + tile1 {A0,A1,Bh0} (6 loads)
  G1_STAGE_A(0, 0, 0) G1_STAGE_A(0, 1, 0) G1_STAGE_B(0, 0, 0) G1_STAGE_B(0, 1, 0)
  G1_STAGE_A(1, 0, 1) G1_STAGE_A(1, 1, 1) G1_STAGE_B(1, 0, 1)
  asm volatile("s_waitcnt vmcnt(6)" ::: "memory");
  BAR();

#pragma unroll 2
  for (int k = 0; k < NK1; ++k) {
    const u16* sAc  = &sA [k & 1][0];
    const u16* sB1c = &sB1[k & 1][0];
    const u16* sB3c = &sB3[k & 1][0];
    const int nb = (k & 1) ^ 1;
    const bool p1 = (k + 1 < NK1), p2 = (k + 2 < NK1);

    G1_PH(0, 0, if (p1) G1_STAGE_B(nb, 1, k + 1))          // stage B-half1(k+1)
    BAR();
    G1_PH(0, 1, if (p2) G1_STAGE_A(k & 1, 0, k + 2))       // stage A-half0(k+2)
    BAR();
    G1_PH(1, 0, )
    BAR();
    G1_PH(1, 1, if (p2) { G1_STAGE_A(k & 1, 1, k + 2) G1_STAGE_B(k & 1, 0, k + 2) })
    if (p1) {
      if (p2) asm volatile("s_waitcnt vmcnt(6)" ::: "memory");
      else    asm volatile("s_waitcnt vmcnt(0)" ::: "memory");
    }
    BAR();
  }

  // epilogue: h = silu(acc1) * acc3
#pragma unroll
  for (int mq = 0; mq < 2; ++mq)
#pragma unroll
    for (int mi = 0; mi < 4; ++mi)
#pragma unroll
      for (int r = 0; r < 4; ++r) {
        const int lrow = mq * 128 + wr * 64 + mi * 16 + lk * 4 + r;
        const int rg = mT * 256 + lrow;
        if (rg < cnt) {
          u16* hrow = h + (size_t)(base + rg) * HID + nT * 128 + wc * 16 + l15;
#pragma unroll
          for (int nq = 0; nq < 2; ++nq) {
            const float a = acc1[mq][nq][mi][r];
            const float b = acc3[mq][nq][mi][r];
            hrow[nq * 64] = f2bf((a / (1.f + __expf(-a))) * b);
          }
        }
      }
}

// ============================================================================
// GEMM2: O = H @ W2^T, scatter f32 rows. BM=256, BN=256, BK=64, 8 waves.
// T1 XCD swizzle: w2 stripe (1.4 MB) L2-resident per XCD.
// ============================================================================

#define G2_STAGE_A(BUF, HH, KT) {                                     \
    char* _d = (char*)&sA[BUF][(HH) * 8192] + t * 16;                 \
    gld16(_d,        ((HH) ? aptr2 : aptr0) + (size_t)(KT) * 64);     \
    gld16(_d + 8192, ((HH) ? aptr3 : aptr1) + (size_t)(KT) * 64); }

#define G2_STAGE_B(BUF, HH, KT) {                                     \
    char* _d = (char*)&sB[BUF][(HH) * 8192] + t * 16;                 \
    gld16(_d,        ((HH) ? bptr2 : bptr0) + (size_t)(KT) * 64);     \
    gld16(_d + 8192, ((HH) ? bptr3 : bptr1) + (size_t)(KT) * 64); }

#define G2_PH(MQ, NQ, ...) {                                                   \
    if ((NQ) == 0) {                                                           \
      _Pragma("unroll") for (int mi = 0; mi < 4; ++mi) {                       \
        af0[mi] = *(const bf16x8*)&sAc[aBase + (MQ)*8192 + mi*1024 + kb0];     \
        af1[mi] = *(const bf16x8*)&sAc[aBase + (MQ)*8192 + mi*1024 + kb1];     \
      }                                                                        \
    }                                                                          \
    _Pragma("unroll") for (int ni = 0; ni < 2; ++ni) {                         \
      bf0[ni] = *(const bf16x8*)&sBc[bBase + (NQ)*8192 + ni*1024 + kb0];       \
      bf1[ni] = *(const bf16x8*)&sBc[bBase + (NQ)*8192 + ni*1024 + kb1];       \
    }                                                                          \
    __VA_ARGS__                                                                \
    BAR();                                                                     \
    __builtin_amdgcn_s_setprio(1);                                             \
    _Pragma("unroll") for (int mi = 0; mi < 4; ++mi)                           \
      _Pragma("unroll") for (int ni = 0; ni < 2; ++ni) {                       \
        acc[MQ][NQ][mi][ni] = MFMA_(af0[mi], bf0[ni], acc[MQ][NQ][mi][ni]);    \
        acc[MQ][NQ][mi][ni] = MFMA_(af1[mi], bf1[ni], acc[MQ][NQ][mi][ni]);    \
      }                                                                        \
    __builtin_amdgcn_s_setprio(0);                                             \
  }

__global__ __launch_bounds__(512, 2) void k_gemm2(
    const u16* __restrict__ hbuf, const u16* __restrict__ w2b,
    const int* __restrict__ meta, const int* __restrict__ idx,
    float* __restrict__ out)
{
  const int e    = blockIdx.z;
  const int cnt  = meta[e];
  const int base = e ? meta[0] : 0;

  // T1 bijective XCD swizzle (per-z nwg = 512, 512 % 8 == 0)
  const int olin    = blockIdx.y * gridDim.x + blockIdx.x;
  const int logical = (olin & 7) * (NWG2 >> 3) + (olin >> 3);
  const int mT      = logical & (NMT - 1);
  const int nT      = logical >> 7;
  if (mT * 256 >= cnt) return;

  __shared__ __attribute__((aligned(16))) u16 sA[2][256 * 64];
  __shared__ __attribute__((aligned(16))) u16 sB[2][256 * 64];

  const int t = threadIdx.x;
  const int srcoff = ((t & 7) ^ ((t >> 3) & 7)) * 8;
  const int r0 = t >> 3;

  const u16 *aptr0, *aptr1, *aptr2, *aptr3;
  {
    int rg;
    rg = mT*256 +   0 + r0; rg = rg < cnt ? rg : cnt-1; aptr0 = hbuf + (size_t)(base+rg)*HID + srcoff;
    rg = mT*256 +  64 + r0; rg = rg < cnt ? rg : cnt-1; aptr1 = hbuf + (size_t)(base+rg)*HID + srcoff;
    rg = mT*256 + 128 + r0; rg = rg < cnt ? rg : cnt-1; aptr2 = hbuf + (size_t)(base+rg)*HID + srcoff;
    rg = mT*256 + 192 + r0; rg = rg < cnt ? rg : cnt-1; aptr3 = hbuf + (size_t)(base+rg)*HID + srcoff;
  }
  const u16 *bptr0, *bptr1, *bptr2, *bptr3;
  {
    const size_t wb = (size_t)e * DIM + (size_t)nT * 256;
    bptr0 = w2b + (wb +       r0) * HID + srcoff;
    bptr1 = w2b + (wb +  64 + r0) * HID + srcoff;
    bptr2 = w2b + (wb + 128 + r0) * HID + srcoff;
    bptr3 = w2b + (wb + 192 + r0) * HID + srcoff;
  }

  const int wid = t >> 6, l = t & 63;
  const int wr = wid >> 2, wc = wid & 3;
  const int l15 = l & 15, lk = l >> 4, l7 = l & 7;
  const int kb0 = ((0 + lk) ^ l7) * 8;
  const int kb1 = ((4 + lk) ^ l7) * 8;
  const int aBase = (wr * 64 + l15) * 64;
  const int bBase = (wc * 32 + l15) * 64;

  f32x4 acc[2][2][4][2] = {};
  bf16x8 af0[4], af1[4], bf0[2], bf1[2];

  // prologue
  G2_STAGE_A(0, 0, 0) G2_STAGE_A(0, 1, 0) G2_STAGE_B(0, 0, 0) G2_STAGE_B(0, 1, 0)
  G2_STAGE_A(1, 0, 1) G2_STAGE_A(1, 1, 1) G2_STAGE_B(1, 0, 1)
  asm volatile("s_waitcnt vmcnt(6)" ::: "memory");
  BAR();

#pragma unroll 2
  for (int k = 0; k < NK2; ++k) {
    const u16* sAc = &sA[k & 1][0];
    const u16* sBc = &sB[k & 1][0];
    const int nb = (k & 1) ^ 1;
    const bool p1 = (k + 1 < NK2), p2 = (k + 2 < NK2);

    G2_PH(0, 0, if (p1) G2_STAGE_B(nb, 1, k + 1))
    BAR();
    G2_PH(0, 1, if (p2) G2_STAGE_A(k & 1, 0, k + 2))
    BAR();
    G2_PH(1, 0, )
    BAR();
    G2_PH(1, 1, if (p2) { G2_STAGE_A(k & 1, 1, k + 2) G2_STAGE_B(k & 1, 0, k + 2) })
    if (p1) {
      if (p2) asm volatile("s_waitcnt vmcnt(6)" ::: "memory");
      else    asm volatile("s_waitcnt vmcnt(0)" ::: "memory");
    }
    BAR();
  }

#pragma unroll
  for (int mq = 0; mq < 2; ++mq)
#pragma unroll
    for (int mi = 0; mi < 4; ++mi)
#pragma unroll
      for (int r = 0; r < 4; ++r) {
        const int lrow = mq * 128 + wr * 64 + mi * 16 + lk * 4 + r;
        const int rg = mT * 256 + lrow;
        if (rg < cnt) {
          const int tok = idx[base + rg];
          float* orow = out + (size_t)tok * DIM + nT * 256 + wc * 32 + l15;
#pragma unroll
          for (int nq = 0; nq < 2; ++nq)
#pragma unroll
            for (int ni = 0; ni < 2; ++ni)
              orow[nq * 128 + ni * 16] = acc[mq][nq][mi][ni][r];
        }
      }
}

// ---------------- RMSNorm in-place on d_out ----------------
__global__ __launch_bounds__(256) void k_rms(
    float* __restrict__ out, const float* __restrict__ nw,
    const int* __restrict__ meta, const int* __restrict__ idx)
{
  const int r = blockIdx.x;
  const int e = (r >= meta[0]) ? 1 : 0;
  const int tok = idx[r];
  float* row = out + (size_t)tok * DIM;
  const int t = threadIdx.x;

  float4 v = ((const float4*)row)[t];
  float ss = v.x * v.x + v.y * v.y + v.z * v.z + v.w * v.w;
#pragma unroll
  for (int off = 32; off; off >>= 1) ss += __shfl_xor(ss, off, 64);

  __shared__ float red[4];
  const int l = t & 63, wv = t >> 6;
  if (l == 0) red[wv] = ss;
  __syncthreads();
  const float tot = red[0] + red[1] + red[2] + red[3];
  const float scale = rsqrtf(tot * (1.0f / DIM) + RMS_EPS);

  const float4 g = ((const float4*)(nw + (size_t)e * DIM))[t];
  v.x *= scale * g.x; v.y *= scale * g.y;
  v.z *= scale * g.z; v.w *= scale * g.w;
  ((float4*)row)[t] = v;
}

// ---------------- launch ----------------
extern "C" void kernel_launch(void* const* d_in, const int* in_sizes, int n_in,
                              void* d_out, int out_size, void* d_ws, size_t ws_size,
                              hipStream_t stream)
{
  const float* x     = (const float*)d_in[0];
  const void*  masks = d_in[1];
  const float* w1    = (const float*)d_in[2];
  const float* w3    = (const float*)d_in[3];
  const float* w2    = (const float*)d_in[4];
  const float* nw    = (const float*)d_in[5];
  float* out = (float*)d_out;

  char* ws = (char*)d_ws;
  constexpr size_t OFF_IDX = 256;
  constexpr size_t OFF_XB  = OFF_IDX + (size_t)NTOK * 4;
  constexpr size_t OFF_W1B = OFF_XB + (size_t)NTOK * DIM * 2;
  constexpr size_t SZ_W    = (size_t)NEXP * HID * DIM * 2;
  constexpr size_t OFF_W3B = OFF_W1B + SZ_W;
  constexpr size_t OFF_W2B = OFF_W3B + SZ_W;
  constexpr size_t OFF_H   = OFF_W2B + SZ_W;

  int* meta = (int*)ws;
  int* idx  = (int*)(ws + OFF_IDX);
  u16* xb   = (u16*)(ws + OFF_XB);
  u16* w1b  = (u16*)(ws + OFF_W1B);
  u16* w3b  = (u16*)(ws + OFF_W3B);
  u16* w2b  = (u16*)(ws + OFF_W2B);
  u16* h    = (u16*)(ws + OFF_H);

  hipMemsetAsync(meta, 0, 16, stream);
  k_count<<<NTOK / 256, 256, 0, stream>>>(masks, meta);
  k_scan<<<1, 64, 0, stream>>>(meta);
  k_fill<<<NTOK / 256, 256, 0, stream>>>(masks, meta, idx);

  const int wn4 = NEXP * HID * DIM / 4;
  k_cvt<<<(wn4 + 255) / 256, 256, 0, stream>>>(w1, w1b, wn4);
  k_cvt<<<(wn4 + 255) / 256, 256, 0, stream>>>(w3, w3b, wn4);
  k_cvt<<<(wn4 + 255) / 256, 256, 0, stream>>>(w2, w2b, wn4);
  const int xn4 = NTOK * DIM / 4;
  k_cvt<<<(xn4 + 255) / 256, 256, 0, stream>>>(x, xb, xn4);

  k_gemm1<<<dim3(HID / 128, NMT, NEXP), 512, 0, stream>>>(
      xb, w1b, w3b, meta, idx, h);
  k_gemm2<<<dim3(DIM / 256, NMT, NEXP), 512, 0, stream>>>(
      h, w2b, meta, idx, out);
  k_rms<<<NTOK, 256, 0, stream>>>(out, nw, meta, idx);
}

// Round 4
// 1340.507 us; speedup vs baseline: 1.1155x; 1.1155x over previous
//
#include <hip/hip_runtime.h>
#include <stdint.h>

#define DIM   1024
#define HID   2816
#define NEXP  2
#define NTOK  32768
#define RMS_EPS 1e-5f
#define NK1 (DIM / 64)   // 16 K-tiles for GEMM1
#define NK2 (HID / 64)   // 44 K-tiles for GEMM2

// grid geometry for XCD swizzle (must match launch)
#define NMT   (NTOK / 256)          // 128 mT blocks launched per expert
#define NNT1  (HID / 128)           // 22 nT for GEMM1
#define NNT2  (DIM / 256)           // 4  nT for GEMM2

typedef unsigned short u16;
typedef unsigned int   u32;
typedef __bf16 bf16_t;
typedef bf16_t bf16x8 __attribute__((ext_vector_type(8)));
typedef float  f32x4  __attribute__((ext_vector_type(4)));

#define BAR() asm volatile("s_barrier" ::: "memory")
#define MFMA_(a,b,c) __builtin_amdgcn_mfma_f32_16x16x32_bf16(a, b, c, 0, 0, 0)

__device__ __forceinline__ u16 f2bf(float f) {
  u32 u = __float_as_uint(f);
  u += 0x7FFFu + ((u >> 16) & 1u);   // RNE
  return (u16)(u >> 16);
}

__device__ __forceinline__ void gld16(void* lds, const void* g) {
  __builtin_amdgcn_global_load_lds(
      (__attribute__((address_space(1))) void*)g,
      (__attribute__((address_space(3))) void*)lds, 16, 0, 0);
}

// ---------------- mask decoding (layout-robust) ----------------
__device__ __forceinline__ int detect_layout(const u32* mi) {
  const int lane = threadIdx.x & 63;
  bool all01 = true, allf = true;
  for (int j = 0; j < 8; ++j) {
    u32 w = mi[j * 64 + lane];
    all01 &= (w <= 1u);
    allf  &= (w == 0u || w == 0x3F800000u);
  }
  unsigned long long b01 = __ballot(all01);
  unsigned long long bfl = __ballot(allf);
  if (b01 == ~0ull) return 0;
  if (bfl == ~0ull) return 1;
  return 2;
}

__device__ __forceinline__ bool mask_at(const void* m, int layout, int e, int n) {
  if (layout == 0) return ((const u32*)m)[e * NTOK + n] != 0u;
  if (layout == 1) return ((const float*)m)[e * NTOK + n] != 0.f;
  return ((const unsigned char*)m)[e * NTOK + n] != 0;
}

__device__ __forceinline__ int label_of(const void* m, int layout, int n) {
  for (int e = 0; e < NEXP; ++e)
    if (mask_at(m, layout, e, n)) return e;
  return 0;
}

__global__ void k_count(const void* __restrict__ masks, int* __restrict__ meta) {
  const int layout = detect_layout((const u32*)masks);
  const int n = blockIdx.x * blockDim.x + threadIdx.x;
  if (n < NTOK) atomicAdd(&meta[label_of(masks, layout, n)], 1);
}

__global__ void k_scan(int* __restrict__ meta) {
  if (threadIdx.x == 0) { meta[2] = 0; meta[3] = meta[0]; }
}

__global__ void k_fill(const void* __restrict__ masks, int* __restrict__ meta,
                       int* __restrict__ idx) {
  const int layout = detect_layout((const u32*)masks);
  const int n = blockIdx.x * blockDim.x + threadIdx.x;
  if (n < NTOK) {
    const int e = label_of(masks, layout, n);
    const int pos = atomicAdd(&meta[2 + e], 1);
    idx[pos] = n;
  }
}

// ---------------- f32 -> bf16 conversion ----------------
__global__ void k_cvt(const float* __restrict__ in, u16* __restrict__ out, int n4) {
  const int i = blockIdx.x * blockDim.x + threadIdx.x;
  if (i >= n4) return;
  const float4 v = ((const float4*)in)[i];
  ushort4 o;
  o.x = f2bf(v.x); o.y = f2bf(v.y); o.z = f2bf(v.z); o.w = f2bf(v.w);
  ((ushort4*)out)[i] = o;
}

// ============================================================================
// GEMM1: h = silu(X@W1^T) * (X@W3^T), gathered rows.
// 8-phase counted-vmcnt schedule. BM=256, BN=128 (dual B), BK=64,
// 8 waves (2M x 4N), 128 KiB LDS (2 dbuf).
// XCD swizzle: XCD c owns mT = c (mod 8), sweeping nT fastest ->
//   each A-panel touched by exactly one XCD (A fetched once from HBM);
//   B reuse distance = 22 blocks < 32-block per-XCD residency (L2-resident).
// ============================================================================

#define G1_STAGE_A(BUF, HH, KT) {                                     \
    char* _d = (char*)&sA[BUF][(HH) * 8192] + t * 16;                 \
    gld16(_d,        ((HH) ? aptr2 : aptr0) + (size_t)(KT) * 64);     \
    gld16(_d + 8192, ((HH) ? aptr3 : aptr1) + (size_t)(KT) * 64); }

#define G1_STAGE_B(BUF, HH, KT) {                                     \
    gld16((char*)&sB1[BUF][(HH) * 4096] + t * 16,                     \
          ((HH) ? b1p1 : b1p0) + (size_t)(KT) * 64);                  \
    gld16((char*)&sB3[BUF][(HH) * 4096] + t * 16,                     \
          ((HH) ? b3p1 : b3p0) + (size_t)(KT) * 64); }

#define G1_PH(MQ, NQ, ...) {                                                   \
    if ((NQ) == 0) {                                                           \
      _Pragma("unroll") for (int mi = 0; mi < 4; ++mi) {                       \
        af0[mi] = *(const bf16x8*)&sAc[aBase + (MQ)*8192 + mi*1024 + kb0];     \
        af1[mi] = *(const bf16x8*)&sAc[aBase + (MQ)*8192 + mi*1024 + kb1];     \
      }                                                                        \
    }                                                                          \
    b1f0 = *(const bf16x8*)&sB1c[bBase + (NQ)*4096 + kb0];                     \
    b1f1 = *(const bf16x8*)&sB1c[bBase + (NQ)*4096 + kb1];                     \
    b3f0 = *(const bf16x8*)&sB3c[bBase + (NQ)*4096 + kb0];                     \
    b3f1 = *(const bf16x8*)&sB3c[bBase + (NQ)*4096 + kb1];                     \
    __VA_ARGS__                                                                \
    BAR();                                                                     \
    __builtin_amdgcn_s_setprio(1);                                             \
    _Pragma("unroll") for (int mi = 0; mi < 4; ++mi) {                         \
      acc1[MQ][NQ][mi] = MFMA_(af0[mi], b1f0, acc1[MQ][NQ][mi]);               \
      acc3[MQ][NQ][mi] = MFMA_(af0[mi], b3f0, acc3[MQ][NQ][mi]);               \
      acc1[MQ][NQ][mi] = MFMA_(af1[mi], b1f1, acc1[MQ][NQ][mi]);               \
      acc3[MQ][NQ][mi] = MFMA_(af1[mi], b3f1, acc3[MQ][NQ][mi]);               \
    }                                                                          \
    __builtin_amdgcn_s_setprio(0);                                             \
  }

__global__ __launch_bounds__(512, 2) void k_gemm1(
    const u16* __restrict__ xb, const u16* __restrict__ w1b,
    const u16* __restrict__ w3b, const int* __restrict__ meta,
    const int* __restrict__ idx, u16* __restrict__ h)
{
  const int e    = blockIdx.z;
  const int cnt  = meta[e];
  const int base = e ? meta[0] : 0;

  // XCD mT-ownership swizzle (bijective: per-z nwg = 2816 % 8 == 0)
  const int olin = blockIdx.y * gridDim.x + blockIdx.x;
  const int xcd  = olin & 7;
  const int j    = olin >> 3;            // [0, 352)
  const int nT   = j % NNT1;             // fast: B stripe cycles
  const int mT   = xcd + ((j / NNT1) << 3);  // XCD-disjoint mT sets
  if (mT * 256 >= cnt) return;

  __shared__ __attribute__((aligned(16))) u16 sA [2][256 * 64];
  __shared__ __attribute__((aligned(16))) u16 sB1[2][128 * 64];
  __shared__ __attribute__((aligned(16))) u16 sB3[2][128 * 64];

  const int t = threadIdx.x;
  const int srcoff = ((t & 7) ^ ((t >> 3) & 7)) * 8;   // pre-swizzled src (u16)
  const int r0 = t >> 3;

  const u16 *aptr0, *aptr1, *aptr2, *aptr3;
  {
    int rg;
    rg = mT*256 +   0 + r0; rg = rg < cnt ? rg : cnt-1; aptr0 = xb + (size_t)idx[base+rg]*DIM + srcoff;
    rg = mT*256 +  64 + r0; rg = rg < cnt ? rg : cnt-1; aptr1 = xb + (size_t)idx[base+rg]*DIM + srcoff;
    rg = mT*256 + 128 + r0; rg = rg < cnt ? rg : cnt-1; aptr2 = xb + (size_t)idx[base+rg]*DIM + srcoff;
    rg = mT*256 + 192 + r0; rg = rg < cnt ? rg : cnt-1; aptr3 = xb + (size_t)idx[base+rg]*DIM + srcoff;
  }
  const u16 *b1p0, *b1p1, *b3p0, *b3p1;
  {
    size_t o0 = ((size_t)e * HID + (size_t)nT * 128 +      r0) * DIM + srcoff;
    size_t o1 = ((size_t)e * HID + (size_t)nT * 128 + 64 + r0) * DIM + srcoff;
    b1p0 = w1b + o0; b1p1 = w1b + o1;
    b3p0 = w3b + o0; b3p1 = w3b + o1;
  }

  const int wid = t >> 6, l = t & 63;
  const int wr = wid >> 2, wc = wid & 3;
  const int l15 = l & 15, lk = l >> 4, l7 = l & 7;
  const int kb0 = ((0 + lk) ^ l7) * 8;
  const int kb1 = ((4 + lk) ^ l7) * 8;
  const int aBase = (wr * 64 + l15) * 64;
  const int bBase = (wc * 16 + l15) * 64;

  f32x4 acc1[2][2][4] = {};
  f32x4 acc3[2][2][4] = {};
  bf16x8 af0[4], af1[4], b1f0, b1f1, b3f0, b3f1;

  // prologue: tile0 full (8 loads) + tile1 {A0,A1,Bh0} (6 loads)
  G1_STAGE_A(0, 0, 0) G1_STAGE_A(0, 1, 0) G1_STAGE_B(0, 0, 0) G1_STAGE_B(0, 1, 0)
  G1_STAGE_A(1, 0, 1) G1_STAGE_A(1, 1, 1) G1_STAGE_B(1, 0, 1)
  asm volatile("s_waitcnt vmcnt(6)" ::: "memory");
  BAR();

#pragma unroll 2
  for (int k = 0; k < NK1; ++k) {
    const u16* sAc  = &sA [k & 1][0];
    const u16* sB1c = &sB1[k & 1][0];
    const u16* sB3c = &sB3[k & 1][0];
    const int nb = (k & 1) ^ 1;
    const bool p1 = (k + 1 < NK1), p2 = (k + 2 < NK1);

    G1_PH(0, 0, if (p1) G1_STAGE_B(nb, 1, k + 1))          // stage B-half1(k+1)
    BAR();
    G1_PH(0, 1, if (p2) G1_STAGE_A(k & 1, 0, k + 2))       // stage A-half0(k+2)
    BAR();
    G1_PH(1, 0, )
    BAR();
    G1_PH(1, 1, if (p2) { G1_STAGE_A(k & 1, 1, k + 2) G1_STAGE_B(k & 1, 0, k + 2) })
    if (p1) {
      if (p2) asm volatile("s_waitcnt vmcnt(6)" ::: "memory");
      else    asm volatile("s_waitcnt vmcnt(0)" ::: "memory");
    }
    BAR();
  }

  // epilogue: h = silu(acc1) * acc3
#pragma unroll
  for (int mq = 0; mq < 2; ++mq)
#pragma unroll
    for (int mi = 0; mi < 4; ++mi)
#pragma unroll
      for (int r = 0; r < 4; ++r) {
        const int lrow = mq * 128 + wr * 64 + mi * 16 + lk * 4 + r;
        const int rg = mT * 256 + lrow;
        if (rg < cnt) {
          u16* hrow = h + (size_t)(base + rg) * HID + nT * 128 + wc * 16 + l15;
#pragma unroll
          for (int nq = 0; nq < 2; ++nq) {
            const float a = acc1[mq][nq][mi][r];
            const float b = acc3[mq][nq][mi][r];
            hrow[nq * 64] = f2bf((a / (1.f + __expf(-a))) * b);
          }
        }
      }
}

// ============================================================================
// GEMM2: O = H @ W2^T, scatter f32 rows. BM=256, BN=256, BK=64, 8 waves.
// Same XCD mT-ownership swizzle: h row-panels fetched once from HBM.
// ============================================================================

#define G2_STAGE_A(BUF, HH, KT) {                                     \
    char* _d = (char*)&sA[BUF][(HH) * 8192] + t * 16;                 \
    gld16(_d,        ((HH) ? aptr2 : aptr0) + (size_t)(KT) * 64);     \
    gld16(_d + 8192, ((HH) ? aptr3 : aptr1) + (size_t)(KT) * 64); }

#define G2_STAGE_B(BUF, HH, KT) {                                     \
    char* _d = (char*)&sB[BUF][(HH) * 8192] + t * 16;                 \
    gld16(_d,        ((HH) ? bptr2 : bptr0) + (size_t)(KT) * 64);     \
    gld16(_d + 8192, ((HH) ? bptr3 : bptr1) + (size_t)(KT) * 64); }

#define G2_PH(MQ, NQ, ...) {                                                   \
    if ((NQ) == 0) {                                                           \
      _Pragma("unroll") for (int mi = 0; mi < 4; ++mi) {                       \
        af0[mi] = *(const bf16x8*)&sAc[aBase + (MQ)*8192 + mi*1024 + kb0];     \
        af1[mi] = *(const bf16x8*)&sAc[aBase + (MQ)*8192 + mi*1024 + kb1];     \
      }                                                                        \
    }                                                                          \
    _Pragma("unroll") for (int ni = 0; ni < 2; ++ni) {                         \
      bf0[ni] = *(const bf16x8*)&sBc[bBase + (NQ)*8192 + ni*1024 + kb0];       \
      bf1[ni] = *(const bf16x8*)&sBc[bBase + (NQ)*8192 + ni*1024 + kb1];       \
    }                                                                          \
    __VA_ARGS__                                                                \
    BAR();                                                                     \
    __builtin_amdgcn_s_setprio(1);                                             \
    _Pragma("unroll") for (int mi = 0; mi < 4; ++mi)                           \
      _Pragma("unroll") for (int ni = 0; ni < 2; ++ni) {                       \
        acc[MQ][NQ][mi][ni] = MFMA_(af0[mi], bf0[ni], acc[MQ][NQ][mi][ni]);    \
        acc[MQ][NQ][mi][ni] = MFMA_(af1[mi], bf1[ni], acc[MQ][NQ][mi][ni]);    \
      }                                                                        \
    __builtin_amdgcn_s_setprio(0);                                             \
  }

__global__ __launch_bounds__(512, 2) void k_gemm2(
    const u16* __restrict__ hbuf, const u16* __restrict__ w2b,
    const int* __restrict__ meta, const int* __restrict__ idx,
    float* __restrict__ out)
{
  const int e    = blockIdx.z;
  const int cnt  = meta[e];
  const int base = e ? meta[0] : 0;

  // XCD mT-ownership swizzle (bijective: per-z nwg = 512 % 8 == 0)
  const int olin = blockIdx.y * gridDim.x + blockIdx.x;
  const int xcd  = olin & 7;
  const int j    = olin >> 3;            // [0, 64)
  const int nT   = j & (NNT2 - 1);
  const int mT   = xcd + ((j >> 2) << 3);
  if (mT * 256 >= cnt) return;

  __shared__ __attribute__((aligned(16))) u16 sA[2][256 * 64];
  __shared__ __attribute__((aligned(16))) u16 sB[2][256 * 64];

  const int t = threadIdx.x;
  const int srcoff = ((t & 7) ^ ((t >> 3) & 7)) * 8;
  const int r0 = t >> 3;

  const u16 *aptr0, *aptr1, *aptr2, *aptr3;
  {
    int rg;
    rg = mT*256 +   0 + r0; rg = rg < cnt ? rg : cnt-1; aptr0 = hbuf + (size_t)(base+rg)*HID + srcoff;
    rg = mT*256 +  64 + r0; rg = rg < cnt ? rg : cnt-1; aptr1 = hbuf + (size_t)(base+rg)*HID + srcoff;
    rg = mT*256 + 128 + r0; rg = rg < cnt ? rg : cnt-1; aptr2 = hbuf + (size_t)(base+rg)*HID + srcoff;
    rg = mT*256 + 192 + r0; rg = rg < cnt ? rg : cnt-1; aptr3 = hbuf + (size_t)(base+rg)*HID + srcoff;
  }
  const u16 *bptr0, *bptr1, *bptr2, *bptr3;
  {
    const size_t wb = (size_t)e * DIM + (size_t)nT * 256;
    bptr0 = w2b + (wb +       r0) * HID + srcoff;
    bptr1 = w2b + (wb +  64 + r0) * HID + srcoff;
    bptr2 = w2b + (wb + 128 + r0) * HID + srcoff;
    bptr3 = w2b + (wb + 192 + r0) * HID + srcoff;
  }

  const int wid = t >> 6, l = t & 63;
  const int wr = wid >> 2, wc = wid & 3;
  const int l15 = l & 15, lk = l >> 4, l7 = l & 7;
  const int kb0 = ((0 + lk) ^ l7) * 8;
  const int kb1 = ((4 + lk) ^ l7) * 8;
  const int aBase = (wr * 64 + l15) * 64;
  const int bBase = (wc * 32 + l15) * 64;

  f32x4 acc[2][2][4][2] = {};
  bf16x8 af0[4], af1[4], bf0[2], bf1[2];

  // prologue
  G2_STAGE_A(0, 0, 0) G2_STAGE_A(0, 1, 0) G2_STAGE_B(0, 0, 0) G2_STAGE_B(0, 1, 0)
  G2_STAGE_A(1, 0, 1) G2_STAGE_A(1, 1, 1) G2_STAGE_B(1, 0, 1)
  asm volatile("s_waitcnt vmcnt(6)" ::: "memory");
  BAR();

#pragma unroll 2
  for (int k = 0; k < NK2; ++k) {
    const u16* sAc = &sA[k & 1][0];
    const u16* sBc = &sB[k & 1][0];
    const int nb = (k & 1) ^ 1;
    const bool p1 = (k + 1 < NK2), p2 = (k + 2 < NK2);

    G2_PH(0, 0, if (p1) G2_STAGE_B(nb, 1, k + 1))
    BAR();
    G2_PH(0, 1, if (p2) G2_STAGE_A(k & 1, 0, k + 2))
    BAR();
    G2_PH(1, 0, )
    BAR();
    G2_PH(1, 1, if (p2) { G2_STAGE_A(k & 1, 1, k + 2) G2_STAGE_B(k & 1, 0, k + 2) })
    if (p1) {
      if (p2) asm volatile("s_waitcnt vmcnt(6)" ::: "memory");
      else    asm volatile("s_waitcnt vmcnt(0)" ::: "memory");
    }
    BAR();
  }

#pragma unroll
  for (int mq = 0; mq < 2; ++mq)
#pragma unroll
    for (int mi = 0; mi < 4; ++mi)
#pragma unroll
      for (int r = 0; r < 4; ++r) {
        const int lrow = mq * 128 + wr * 64 + mi * 16 + lk * 4 + r;
        const int rg = mT * 256 + lrow;
        if (rg < cnt) {
          const int tok = idx[base + rg];
          float* orow = out + (size_t)tok * DIM + nT * 256 + wc * 32 + l15;
#pragma unroll
          for (int nq = 0; nq < 2; ++nq)
#pragma unroll
            for (int ni = 0; ni < 2; ++ni)
              orow[nq * 128 + ni * 16] = acc[mq][nq][mi][ni][r];
        }
      }
}

// ---------------- RMSNorm in-place on d_out ----------------
__global__ __launch_bounds__(256) void k_rms(
    float* __restrict__ out, const float* __restrict__ nw,
    const int* __restrict__ meta, const int* __restrict__ idx)
{
  const int r = blockIdx.x;
  const int e = (r >= meta[0]) ? 1 : 0;
  const int tok = idx[r];
  float* row = out + (size_t)tok * DIM;
  const int t = threadIdx.x;

  float4 v = ((const float4*)row)[t];
  float ss = v.x * v.x + v.y * v.y + v.z * v.z + v.w * v.w;
#pragma unroll
  for (int off = 32; off; off >>= 1) ss += __shfl_xor(ss, off, 64);

  __shared__ float red[4];
  const int l = t & 63, wv = t >> 6;
  if (l == 0) red[wv] = ss;
  __syncthreads();
  const float tot = red[0] + red[1] + red[2] + red[3];
  const float scale = rsqrtf(tot * (1.0f / DIM) + RMS_EPS);

  const float4 g = ((const float4*)(nw + (size_t)e * DIM))[t];
  v.x *= scale * g.x; v.y *= scale * g.y;
  v.z *= scale * g.z; v.w *= scale * g.w;
  ((float4*)row)[t] = v;
}

// ---------------- launch ----------------
extern "C" void kernel_launch(void* const* d_in, const int* in_sizes, int n_in,
                              void* d_out, int out_size, void* d_ws, size_t ws_size,
                              hipStream_t stream)
{
  const float* x     = (const float*)d_in[0];
  const void*  masks = d_in[1];
  const float* w1    = (const float*)d_in[2];
  const float* w3    = (const float*)d_in[3];
  const float* w2    = (const float*)d_in[4];
  const float* nw    = (const float*)d_in[5];
  float* out = (float*)d_out;

  char* ws = (char*)d_ws;
  constexpr size_t OFF_IDX = 256;
  constexpr size_t OFF_XB  = OFF_IDX + (size_t)NTOK * 4;
  constexpr size_t OFF_W1B = OFF_XB + (size_t)NTOK * DIM * 2;
  constexpr size_t SZ_W    = (size_t)NEXP * HID * DIM * 2;
  constexpr size_t OFF_W3B = OFF_W1B + SZ_W;
  constexpr size_t OFF_W2B = OFF_W3B + SZ_W;
  constexpr size_t OFF_H   = OFF_W2B + SZ_W;

  int* meta = (int*)ws;
  int* idx  = (int*)(ws + OFF_IDX);
  u16* xb   = (u16*)(ws + OFF_XB);
  u16* w1b  = (u16*)(ws + OFF_W1B);
  u16* w3b  = (u16*)(ws + OFF_W3B);
  u16* w2b  = (u16*)(ws + OFF_W2B);
  u16* h    = (u16*)(ws + OFF_H);

  hipMemsetAsync(meta, 0, 16, stream);
  k_count<<<NTOK / 256, 256, 0, stream>>>(masks, meta);
  k_scan<<<1, 64, 0, stream>>>(meta);
  k_fill<<<NTOK / 256, 256, 0, stream>>>(masks, meta, idx);

  const int wn4 = NEXP * HID * DIM / 4;
  k_cvt<<<(wn4 + 255) / 256, 256, 0, stream>>>(w1, w1b, wn4);
  k_cvt<<<(wn4 + 255) / 256, 256, 0, stream>>>(w3, w3b, wn4);
  k_cvt<<<(wn4 + 255) / 256, 256, 0, stream>>>(w2, w2b, wn4);
  const int xn4 = NTOK * DIM / 4;
  k_cvt<<<(xn4 + 255) / 256, 256, 0, stream>>>(x, xb, xn4);

  k_gemm1<<<dim3(NNT1, NMT, NEXP), 512, 0, stream>>>(
      xb, w1b, w3b, meta, idx, h);
  k_gemm2<<<dim3(NNT2, NMT, NEXP), 512, 0, stream>>>(
      h, w2b, meta, idx, out);
  k_rms<<<NTOK, 256, 0, stream>>>(out, nw, meta, idx);
}

// Round 5
// 1295.424 us; speedup vs baseline: 1.1543x; 1.0348x over previous
//
#include <hip/hip_runtime.h>
#include <stdint.h>

#define DIM   1024
#define HID   2816
#define NEXP  2
#define NTOK  32768
#define RMS_EPS 1e-5f
#define NK1   16            // K-tiles per item, GEMM1 (DIM/64)
#define NK2   44            // K-tiles per item, GEMM2 (HID/64)
#define NNT1  22            // HID/128 column tiles, GEMM1
#define NNT2  4             // DIM/256 column tiles, GEMM2

typedef unsigned short u16;
typedef unsigned int   u32;
typedef __bf16 bf16_t;
typedef bf16_t bf16x8 __attribute__((ext_vector_type(8)));
typedef float  f32x4  __attribute__((ext_vector_type(4)));

#define BAR() asm volatile("s_barrier" ::: "memory")
#define WAIT6() asm volatile("s_waitcnt vmcnt(6)" ::: "memory")
#define WAIT0() asm volatile("s_waitcnt vmcnt(0)" ::: "memory")
#define MFMA_(a,b,c) __builtin_amdgcn_mfma_f32_16x16x32_bf16(a, b, c, 0, 0, 0)

__device__ __forceinline__ u16 f2bf(float f) {
  u32 u = __float_as_uint(f);
  u += 0x7FFFu + ((u >> 16) & 1u);   // RNE
  return (u16)(u >> 16);
}

__device__ __forceinline__ void gld16(void* lds, const void* g) {
  __builtin_amdgcn_global_load_lds(
      (__attribute__((address_space(1))) void*)g,
      (__attribute__((address_space(3))) void*)lds, 16, 0, 0);
}

// ---------------- mask decoding (layout-robust) ----------------
__device__ __forceinline__ int detect_layout(const u32* mi) {
  const int lane = threadIdx.x & 63;
  bool all01 = true, allf = true;
  for (int j = 0; j < 8; ++j) {
    u32 w = mi[j * 64 + lane];
    all01 &= (w <= 1u);
    allf  &= (w == 0u || w == 0x3F800000u);
  }
  unsigned long long b01 = __ballot(all01);
  unsigned long long bfl = __ballot(allf);
  if (b01 == ~0ull) return 0;
  if (bfl == ~0ull) return 1;
  return 2;
}

__device__ __forceinline__ bool mask_at(const void* m, int layout, int e, int n) {
  if (layout == 0) return ((const u32*)m)[e * NTOK + n] != 0u;
  if (layout == 1) return ((const float*)m)[e * NTOK + n] != 0.f;
  return ((const unsigned char*)m)[e * NTOK + n] != 0;
}

__device__ __forceinline__ int label_of(const void* m, int layout, int n) {
  for (int e = 0; e < NEXP; ++e)
    if (mask_at(m, layout, e, n)) return e;
  return 0;
}

__global__ void k_count(const void* __restrict__ masks, int* __restrict__ meta) {
  const int layout = detect_layout((const u32*)masks);
  const int n = blockIdx.x * blockDim.x + threadIdx.x;
  if (n < NTOK) atomicAdd(&meta[label_of(masks, layout, n)], 1);
}

__global__ void k_scan(int* __restrict__ meta) {
  if (threadIdx.x == 0) { meta[2] = 0; meta[3] = meta[0]; }
}

__global__ void k_fill(const void* __restrict__ masks, int* __restrict__ meta,
                       int* __restrict__ idx) {
  const int layout = detect_layout((const u32*)masks);
  const int n = blockIdx.x * blockDim.x + threadIdx.x;
  if (n < NTOK) {
    const int e = label_of(masks, layout, n);
    const int pos = atomicAdd(&meta[2 + e], 1);
    idx[pos] = n;
  }
}

// ---------------- f32 -> bf16 conversion ----------------
__global__ void k_cvt(const float* __restrict__ in, u16* __restrict__ out, int n4) {
  const int i = blockIdx.x * blockDim.x + threadIdx.x;
  if (i >= n4) return;
  const float4 v = ((const float4*)in)[i];
  ushort4 o;
  o.x = f2bf(v.x); o.y = f2bf(v.y); o.z = f2bf(v.z); o.w = f2bf(v.w);
  ((ushort4*)out)[i] = o;
}

// ============================================================================
// GEMM1 (persistent): h = silu(X@W1^T) * (X@W3^T), gathered rows.
// 256 blocks (1/CU), 8 waves, BM=256, BN=128 dual-B, BK=64, 128 KiB LDS.
// Virtual-XCD c = bid&7 owns mT ≡ c (mod 8); items ordered nT-inner so the
// 32 lockstep blocks of an XCD share A-halftiles in L2.
// Cross-item seamless pipeline: last 2 K-steps peeled, prefetch slots
// redirected to next item's pointers; vmcnt(6) cadence unbroken.
// ============================================================================

#define ST1A(BUF, HH, P_, KT) {                                        \
    char* _d = (char*)&sA[BUF][(HH) * 8192] + t * 16;                  \
    gld16(_d,        ((HH) ? P_.a2 : P_.a0) + (size_t)(KT) * 64);      \
    gld16(_d + 8192, ((HH) ? P_.a3 : P_.a1) + (size_t)(KT) * 64); }

#define ST1B(BUF, HH, P_, KT) {                                                 \
    gld16((char*)&sB1[BUF][(HH) * 4096] + t * 16,                               \
          ((HH) ? P_.b11 : P_.b10) + (size_t)(KT) * 64);                        \
    gld16((char*)&sB3[BUF][(HH) * 4096] + t * 16,                               \
          ((HH) ? P_.b31 : P_.b30) + (size_t)(KT) * 64); }

#define G1_PH(MQ, NQ, ...) {                                                   \
    if ((NQ) == 0) {                                                           \
      _Pragma("unroll") for (int mi = 0; mi < 4; ++mi) {                       \
        af0[mi] = *(const bf16x8*)&sAc[aBase + (MQ)*8192 + mi*1024 + kb0];     \
        af1[mi] = *(const bf16x8*)&sAc[aBase + (MQ)*8192 + mi*1024 + kb1];     \
      }                                                                        \
    }                                                                          \
    b1f0 = *(const bf16x8*)&sB1c[bBase + (NQ)*4096 + kb0];                     \
    b1f1 = *(const bf16x8*)&sB1c[bBase + (NQ)*4096 + kb1];                     \
    b3f0 = *(const bf16x8*)&sB3c[bBase + (NQ)*4096 + kb0];                     \
    b3f1 = *(const bf16x8*)&sB3c[bBase + (NQ)*4096 + kb1];                     \
    __VA_ARGS__                                                                \
    BAR();                                                                     \
    __builtin_amdgcn_s_setprio(1);                                             \
    _Pragma("unroll") for (int mi = 0; mi < 4; ++mi) {                         \
      acc1[MQ][NQ][mi] = MFMA_(af0[mi], b1f0, acc1[MQ][NQ][mi]);               \
      acc3[MQ][NQ][mi] = MFMA_(af0[mi], b3f0, acc3[MQ][NQ][mi]);               \
      acc1[MQ][NQ][mi] = MFMA_(af1[mi], b1f1, acc1[MQ][NQ][mi]);               \
      acc3[MQ][NQ][mi] = MFMA_(af1[mi], b3f1, acc3[MQ][NQ][mi]);               \
    }                                                                          \
    __builtin_amdgcn_s_setprio(0);                                             \
  }

#define SETUP1(P_, IT) {                                                        \
    int _it = (IT);                                                            \
    int _m  = c + ((_it / NNT1) << 3);                                         \
    P_.nT   = _it % NNT1;                                                      \
    int _e  = _m >= nmt0;                                                      \
    P_.mT   = _e ? _m - nmt0 : _m;                                             \
    P_.cnt  = _e ? cnt1 : cnt0;                                                \
    P_.bas  = _e ? cnt0 : 0;                                                   \
    int _rg;                                                                   \
    _rg = P_.mT*256       + r0; _rg = _rg < P_.cnt ? _rg : P_.cnt-1;           \
    P_.a0 = xb + (size_t)idx[P_.bas+_rg]*DIM + srcoff;                         \
    _rg = P_.mT*256 +  64 + r0; _rg = _rg < P_.cnt ? _rg : P_.cnt-1;           \
    P_.a1 = xb + (size_t)idx[P_.bas+_rg]*DIM + srcoff;                         \
    _rg = P_.mT*256 + 128 + r0; _rg = _rg < P_.cnt ? _rg : P_.cnt-1;           \
    P_.a2 = xb + (size_t)idx[P_.bas+_rg]*DIM + srcoff;                         \
    _rg = P_.mT*256 + 192 + r0; _rg = _rg < P_.cnt ? _rg : P_.cnt-1;           \
    P_.a3 = xb + (size_t)idx[P_.bas+_rg]*DIM + srcoff;                         \
    size_t _o = ((size_t)_e * HID + (size_t)P_.nT * 128 + r0) * DIM + srcoff;  \
    P_.b10 = w1b + _o; P_.b11 = w1b + _o + (size_t)64 * DIM;                   \
    P_.b30 = w3b + _o; P_.b31 = w3b + _o + (size_t)64 * DIM; }

__global__ __launch_bounds__(512, 2) void k_gemm1(
    const u16* __restrict__ xb, const u16* __restrict__ w1b,
    const u16* __restrict__ w3b, const int* __restrict__ meta,
    const int* __restrict__ idx, u16* __restrict__ h)
{
  const int cnt0 = meta[0], cnt1 = meta[1];
  const int nmt0 = (cnt0 + 255) >> 8;
  const int nmt  = nmt0 + ((cnt1 + 255) >> 8);
  const int c = blockIdx.x & 7, q = blockIdx.x >> 3;
  const int mcnt  = (nmt > c) ? (((nmt - 1 - c) >> 3) + 1) : 0;
  const int items = mcnt * NNT1;
  int i = q;
  if (i >= items) return;

  __shared__ __attribute__((aligned(16))) u16 sA [2][256 * 64];
  __shared__ __attribute__((aligned(16))) u16 sB1[2][128 * 64];
  __shared__ __attribute__((aligned(16))) u16 sB3[2][128 * 64];

  const int t = threadIdx.x;
  const int srcoff = ((t & 7) ^ ((t >> 3) & 7)) * 8;   // pre-swizzled src (u16)
  const int r0 = t >> 3;
  const int wid = t >> 6, l = t & 63;
  const int wr = wid >> 2, wc = wid & 3;
  const int l15 = l & 15, lk = l >> 4, l7 = l & 7;
  const int kb0 = ((0 + lk) ^ l7) * 8;
  const int kb1 = ((4 + lk) ^ l7) * 8;
  const int aBase = (wr * 64 + l15) * 64;
  const int bBase = (wc * 16 + l15) * 64;

  struct P { const u16 *a0,*a1,*a2,*a3,*b10,*b11,*b30,*b31; int mT,cnt,bas,nT; };
  P cur, nxt;
  SETUP1(cur, i)
  bool hasN = (i + 32) < items;
  if (hasN) { SETUP1(nxt, i + 32) } else { nxt = cur; }

  f32x4 acc1[2][2][4] = {};
  f32x4 acc3[2][2][4] = {};
  bf16x8 af0[4], af1[4], b1f0, b1f1, b3f0, b3f1;

  // prologue: step0 full (8 loads) + step1 {A0,A1,Bh0} (6 loads)
  ST1A(0, 0, cur, 0) ST1A(0, 1, cur, 0) ST1B(0, 0, cur, 0) ST1B(0, 1, cur, 0)
  ST1A(1, 0, cur, 1) ST1A(1, 1, cur, 1) ST1B(1, 0, cur, 1)
  WAIT6();
  BAR();

  for (;;) {
#pragma unroll 2
    for (int k = 0; k < NK1 - 2; ++k) {
      const u16* sAc  = &sA [k & 1][0];
      const u16* sB1c = &sB1[k & 1][0];
      const u16* sB3c = &sB3[k & 1][0];
      G1_PH(0, 0, ST1B((k & 1) ^ 1, 1, cur, k + 1))
      BAR();
      G1_PH(0, 1, ST1A(k & 1, 0, cur, k + 2))
      BAR();
      G1_PH(1, 0, )
      BAR();
      G1_PH(1, 1, ST1A(k & 1, 1, cur, k + 2) ST1B(k & 1, 0, cur, k + 2))
      WAIT6();
      BAR();
    }
    {   // k = NK1-2 (14): prefetch slots k+2 -> next item's step 0
      const u16* sAc  = &sA [0][0];
      const u16* sB1c = &sB1[0][0];
      const u16* sB3c = &sB3[0][0];
      G1_PH(0, 0, ST1B(1, 1, cur, 15))
      BAR();
      G1_PH(0, 1, if (hasN) ST1A(0, 0, nxt, 0))
      BAR();
      G1_PH(1, 0, )
      BAR();
      G1_PH(1, 1, if (hasN) { ST1A(0, 1, nxt, 0) ST1B(0, 0, nxt, 0) })
      if (hasN) WAIT6(); else WAIT0();
      BAR();
    }
    {   // k = NK1-1 (15): prefetch slots -> next item's steps 0/1
      const u16* sAc  = &sA [1][0];
      const u16* sB1c = &sB1[1][0];
      const u16* sB3c = &sB3[1][0];
      G1_PH(0, 0, if (hasN) ST1B(0, 1, nxt, 0))
      BAR();
      G1_PH(0, 1, if (hasN) ST1A(1, 0, nxt, 1))
      BAR();
      G1_PH(1, 0, )
      BAR();
      G1_PH(1, 1, if (hasN) { ST1A(1, 1, nxt, 1) ST1B(1, 0, nxt, 1) })
      if (hasN) WAIT6();
      BAR();
    }

    // epilogue: h = silu(acc1) * acc3 (overlaps next item's in-flight stages)
#pragma unroll
    for (int mq = 0; mq < 2; ++mq)
#pragma unroll
      for (int mi = 0; mi < 4; ++mi)
#pragma unroll
        for (int r = 0; r < 4; ++r) {
          const int lrow = mq * 128 + wr * 64 + mi * 16 + lk * 4 + r;
          const int rg = cur.mT * 256 + lrow;
          if (rg < cur.cnt) {
            u16* hrow = h + (size_t)(cur.bas + rg) * HID + cur.nT * 128 + wc * 16 + l15;
#pragma unroll
            for (int nq = 0; nq < 2; ++nq) {
              const float a = acc1[mq][nq][mi][r];
              const float b = acc3[mq][nq][mi][r];
              hrow[nq * 64] = f2bf((a / (1.f + __expf(-a))) * b);
            }
          }
        }

    if (!hasN) break;
    cur = nxt;
    i += 32;
    hasN = (i + 32) < items;
    if (hasN) SETUP1(nxt, i + 32)
#pragma unroll
    for (int a_ = 0; a_ < 2; ++a_)
#pragma unroll
      for (int b_ = 0; b_ < 2; ++b_)
#pragma unroll
        for (int m_ = 0; m_ < 4; ++m_) {
          acc1[a_][b_][m_] = (f32x4){0.f, 0.f, 0.f, 0.f};
          acc3[a_][b_][m_] = (f32x4){0.f, 0.f, 0.f, 0.f};
        }
  }
}

// ============================================================================
// GEMM2 (persistent): O = H @ W2^T, scatter f32 rows.
// 256 blocks, BM=256, BN=256, BK=64, 8 waves, same seamless item pipeline.
// ============================================================================

#define ST2A(BUF, HH, P_, KT) {                                        \
    char* _d = (char*)&sA[BUF][(HH) * 8192] + t * 16;                  \
    gld16(_d,        ((HH) ? P_.a2 : P_.a0) + (size_t)(KT) * 64);      \
    gld16(_d + 8192, ((HH) ? P_.a3 : P_.a1) + (size_t)(KT) * 64); }

#define ST2B(BUF, HH, P_, KT) {                                        \
    char* _d = (char*)&sB[BUF][(HH) * 8192] + t * 16;                  \
    gld16(_d,        ((HH) ? P_.b2 : P_.b0) + (size_t)(KT) * 64);      \
    gld16(_d + 8192, ((HH) ? P_.b3 : P_.b1) + (size_t)(KT) * 64); }

#define G2_PH(MQ, NQ, ...) {                                                   \
    if ((NQ) == 0) {                                                           \
      _Pragma("unroll") for (int mi = 0; mi < 4; ++mi) {                       \
        af0[mi] = *(const bf16x8*)&sAc[aBase + (MQ)*8192 + mi*1024 + kb0];     \
        af1[mi] = *(const bf16x8*)&sAc[aBase + (MQ)*8192 + mi*1024 + kb1];     \
      }                                                                        \
    }                                                                          \
    _Pragma("unroll") for (int ni = 0; ni < 2; ++ni) {                         \
      bf0[ni] = *(const bf16x8*)&sBc[bBase + (NQ)*8192 + ni*1024 + kb0];       \
      bf1[ni] = *(const bf16x8*)&sBc[bBase + (NQ)*8192 + ni*1024 + kb1];       \
    }                                                                          \
    __VA_ARGS__                                                                \
    BAR();                                                                     \
    __builtin_amdgcn_s_setprio(1);                                             \
    _Pragma("unroll") for (int mi = 0; mi < 4; ++mi)                           \
      _Pragma("unroll") for (int ni = 0; ni < 2; ++ni) {                       \
        acc[MQ][NQ][mi][ni] = MFMA_(af0[mi], bf0[ni], acc[MQ][NQ][mi][ni]);    \
        acc[MQ][NQ][mi][ni] = MFMA_(af1[mi], bf1[ni], acc[MQ][NQ][mi][ni]);    \
      }                                                                        \
    __builtin_amdgcn_s_setprio(0);                                             \
  }

#define SETUP2(P_, IT) {                                                        \
    int _it = (IT);                                                            \
    int _m  = c + ((_it >> 2) << 3);                                           \
    P_.nT   = _it & 3;                                                         \
    int _e  = _m >= nmt0;                                                      \
    P_.mT   = _e ? _m - nmt0 : _m;                                             \
    P_.cnt  = _e ? cnt1 : cnt0;                                                \
    P_.bas  = _e ? cnt0 : 0;                                                   \
    int _rg;                                                                   \
    _rg = P_.mT*256       + r0; _rg = _rg < P_.cnt ? _rg : P_.cnt-1;           \
    P_.a0 = hbuf + (size_t)(P_.bas+_rg)*HID + srcoff;                          \
    _rg = P_.mT*256 +  64 + r0; _rg = _rg < P_.cnt ? _rg : P_.cnt-1;           \
    P_.a1 = hbuf + (size_t)(P_.bas+_rg)*HID + srcoff;                          \
    _rg = P_.mT*256 + 128 + r0; _rg = _rg < P_.cnt ? _rg : P_.cnt-1;           \
    P_.a2 = hbuf + (size_t)(P_.bas+_rg)*HID + srcoff;                          \
    _rg = P_.mT*256 + 192 + r0; _rg = _rg < P_.cnt ? _rg : P_.cnt-1;           \
    P_.a3 = hbuf + (size_t)(P_.bas+_rg)*HID + srcoff;                          \
    size_t _wb = ((size_t)_e * DIM + (size_t)P_.nT * 256 + r0) * HID + srcoff; \
    P_.b0 = w2b + _wb;                                                         \
    P_.b1 = w2b + _wb + (size_t) 64 * HID;                                     \
    P_.b2 = w2b + _wb + (size_t)128 * HID;                                     \
    P_.b3 = w2b + _wb + (size_t)192 * HID; }

__global__ __launch_bounds__(512, 2) void k_gemm2(
    const u16* __restrict__ hbuf, const u16* __restrict__ w2b,
    const int* __restrict__ meta, const int* __restrict__ idx,
    float* __restrict__ out)
{
  const int cnt0 = meta[0], cnt1 = meta[1];
  const int nmt0 = (cnt0 + 255) >> 8;
  const int nmt  = nmt0 + ((cnt1 + 255) >> 8);
  const int c = blockIdx.x & 7, q = blockIdx.x >> 3;
  const int mcnt  = (nmt > c) ? (((nmt - 1 - c) >> 3) + 1) : 0;
  const int items = mcnt * NNT2;
  int i = q;
  if (i >= items) return;

  __shared__ __attribute__((aligned(16))) u16 sA[2][256 * 64];
  __shared__ __attribute__((aligned(16))) u16 sB[2][256 * 64];

  const int t = threadIdx.x;
  const int srcoff = ((t & 7) ^ ((t >> 3) & 7)) * 8;
  const int r0 = t >> 3;
  const int wid = t >> 6, l = t & 63;
  const int wr = wid >> 2, wc = wid & 3;
  const int l15 = l & 15, lk = l >> 4, l7 = l & 7;
  const int kb0 = ((0 + lk) ^ l7) * 8;
  const int kb1 = ((4 + lk) ^ l7) * 8;
  const int aBase = (wr * 64 + l15) * 64;
  const int bBase = (wc * 32 + l15) * 64;

  struct P { const u16 *a0,*a1,*a2,*a3,*b0,*b1,*b2,*b3; int mT,cnt,bas,nT; };
  P cur, nxt;
  SETUP2(cur, i)
  bool hasN = (i + 32) < items;
  if (hasN) { SETUP2(nxt, i + 32) } else { nxt = cur; }

  f32x4 acc[2][2][4][2] = {};
  bf16x8 af0[4], af1[4], bf0[2], bf1[2];

  ST2A(0, 0, cur, 0) ST2A(0, 1, cur, 0) ST2B(0, 0, cur, 0) ST2B(0, 1, cur, 0)
  ST2A(1, 0, cur, 1) ST2A(1, 1, cur, 1) ST2B(1, 0, cur, 1)
  WAIT6();
  BAR();

  for (;;) {
#pragma unroll 2
    for (int k = 0; k < NK2 - 2; ++k) {
      const u16* sAc = &sA[k & 1][0];
      const u16* sBc = &sB[k & 1][0];
      G2_PH(0, 0, ST2B((k & 1) ^ 1, 1, cur, k + 1))
      BAR();
      G2_PH(0, 1, ST2A(k & 1, 0, cur, k + 2))
      BAR();
      G2_PH(1, 0, )
      BAR();
      G2_PH(1, 1, ST2A(k & 1, 1, cur, k + 2) ST2B(k & 1, 0, cur, k + 2))
      WAIT6();
      BAR();
    }
    {   // k = NK2-2 (42)
      const u16* sAc = &sA[0][0];
      const u16* sBc = &sB[0][0];
      G2_PH(0, 0, ST2B(1, 1, cur, NK2 - 1))
      BAR();
      G2_PH(0, 1, if (hasN) ST2A(0, 0, nxt, 0))
      BAR();
      G2_PH(1, 0, )
      BAR();
      G2_PH(1, 1, if (hasN) { ST2A(0, 1, nxt, 0) ST2B(0, 0, nxt, 0) })
      if (hasN) WAIT6(); else WAIT0();
      BAR();
    }
    {   // k = NK2-1 (43)
      const u16* sAc = &sA[1][0];
      const u16* sBc = &sB[1][0];
      G2_PH(0, 0, if (hasN) ST2B(0, 1, nxt, 0))
      BAR();
      G2_PH(0, 1, if (hasN) ST2A(1, 0, nxt, 1))
      BAR();
      G2_PH(1, 0, )
      BAR();
      G2_PH(1, 1, if (hasN) { ST2A(1, 1, nxt, 1) ST2B(1, 0, nxt, 1) })
      if (hasN) WAIT6();
      BAR();
    }

#pragma unroll
    for (int mq = 0; mq < 2; ++mq)
#pragma unroll
      for (int mi = 0; mi < 4; ++mi)
#pragma unroll
        for (int r = 0; r < 4; ++r) {
          const int lrow = mq * 128 + wr * 64 + mi * 16 + lk * 4 + r;
          const int rg = cur.mT * 256 + lrow;
          if (rg < cur.cnt) {
            const int tok = idx[cur.bas + rg];
            float* orow = out + (size_t)tok * DIM + cur.nT * 256 + wc * 32 + l15;
#pragma unroll
            for (int nq = 0; nq < 2; ++nq)
#pragma unroll
              for (int ni = 0; ni < 2; ++ni)
                orow[nq * 128 + ni * 16] = acc[mq][nq][mi][ni][r];
          }
        }

    if (!hasN) break;
    cur = nxt;
    i += 32;
    hasN = (i + 32) < items;
    if (hasN) SETUP2(nxt, i + 32)
#pragma unroll
    for (int a_ = 0; a_ < 2; ++a_)
#pragma unroll
      for (int b_ = 0; b_ < 2; ++b_)
#pragma unroll
        for (int m_ = 0; m_ < 4; ++m_)
#pragma unroll
          for (int n_ = 0; n_ < 2; ++n_)
            acc[a_][b_][m_][n_] = (f32x4){0.f, 0.f, 0.f, 0.f};
  }
}

// ---------------- RMSNorm in-place on d_out ----------------
__global__ __launch_bounds__(256) void k_rms(
    float* __restrict__ out, const float* __restrict__ nw,
    const int* __restrict__ meta, const int* __restrict__ idx)
{
  const int r = blockIdx.x;
  const int e = (r >= meta[0]) ? 1 : 0;
  const int tok = idx[r];
  float* row = out + (size_t)tok * DIM;
  const int t = threadIdx.x;

  float4 v = ((const float4*)row)[t];
  float ss = v.x * v.x + v.y * v.y + v.z * v.z + v.w * v.w;
#pragma unroll
  for (int off = 32; off; off >>= 1) ss += __shfl_xor(ss, off, 64);

  __shared__ float red[4];
  const int l = t & 63, wv = t >> 6;
  if (l == 0) red[wv] = ss;
  __syncthreads();
  const float tot = red[0] + red[1] + red[2] + red[3];
  const float scale = rsqrtf(tot * (1.0f / DIM) + RMS_EPS);

  const float4 g = ((const float4*)(nw + (size_t)e * DIM))[t];
  v.x *= scale * g.x; v.y *= scale * g.y;
  v.z *= scale * g.z; v.w *= scale * g.w;
  ((float4*)row)[t] = v;
}

// ---------------- launch ----------------
extern "C" void kernel_launch(void* const* d_in, const int* in_sizes, int n_in,
                              void* d_out, int out_size, void* d_ws, size_t ws_size,
                              hipStream_t stream)
{
  const float* x     = (const float*)d_in[0];
  const void*  masks = d_in[1];
  const float* w1    = (const float*)d_in[2];
  const float* w3    = (const float*)d_in[3];
  const float* w2    = (const float*)d_in[4];
  const float* nw    = (const float*)d_in[5];
  float* out = (float*)d_out;

  char* ws = (char*)d_ws;
  constexpr size_t OFF_IDX = 256;
  constexpr size_t OFF_XB  = OFF_IDX + (size_t)NTOK * 4;
  constexpr size_t OFF_W1B = OFF_XB + (size_t)NTOK * DIM * 2;
  constexpr size_t SZ_W    = (size_t)NEXP * HID * DIM * 2;
  constexpr size_t OFF_W3B = OFF_W1B + SZ_W;
  constexpr size_t OFF_W2B = OFF_W3B + SZ_W;
  constexpr size_t OFF_H   = OFF_W2B + SZ_W;

  int* meta = (int*)ws;
  int* idx  = (int*)(ws + OFF_IDX);
  u16* xb   = (u16*)(ws + OFF_XB);
  u16* w1b  = (u16*)(ws + OFF_W1B);
  u16* w3b  = (u16*)(ws + OFF_W3B);
  u16* w2b  = (u16*)(ws + OFF_W2B);
  u16* h    = (u16*)(ws + OFF_H);

  hipMemsetAsync(meta, 0, 16, stream);
  k_count<<<NTOK / 256, 256, 0, stream>>>(masks, meta);
  k_scan<<<1, 64, 0, stream>>>(meta);
  k_fill<<<NTOK / 256, 256, 0, stream>>>(masks, meta, idx);

  const int wn4 = NEXP * HID * DIM / 4;
  k_cvt<<<(wn4 + 255) / 256, 256, 0, stream>>>(w1, w1b, wn4);
  k_cvt<<<(wn4 + 255) / 256, 256, 0, stream>>>(w3, w3b, wn4);
  k_cvt<<<(wn4 + 255) / 256, 256, 0, stream>>>(w2, w2b, wn4);
  const int xn4 = NTOK * DIM / 4;
  k_cvt<<<(xn4 + 255) / 256, 256, 0, stream>>>(x, xb, xn4);

  k_gemm1<<<256, 512, 0, stream>>>(xb, w1b, w3b, meta, idx, h);
  k_gemm2<<<256, 512, 0, stream>>>(h, w2b, meta, idx, out);
  k_rms<<<NTOK, 256, 0, stream>>>(out, nw, meta, idx);
}

// Round 6
// 833.160 us; speedup vs baseline: 1.7947x; 1.5548x over previous
//
#include <hip/hip_runtime.h>
#include <stdint.h>

#define DIM   1024
#define HID   2816
#define NEXP  2
#define NTOK  32768
#define RMS_EPS 1e-5f
#define NK1   16            // K-tiles per item, GEMM1 (DIM/64)
#define NK2   44            // K-tiles per item, GEMM2 (HID/64)
#define NNT1  22            // HID/128 column tiles, GEMM1
#define NNT2  4             // DIM/256 column tiles, GEMM2

typedef unsigned short u16;
typedef unsigned int   u32;
typedef __bf16 bf16_t;
typedef bf16_t bf16x8 __attribute__((ext_vector_type(8)));
typedef float  f32x4  __attribute__((ext_vector_type(4)));

#define BAR() asm volatile("s_barrier" ::: "memory")
#define WAIT6() asm volatile("s_waitcnt vmcnt(6)" ::: "memory")
#define WAIT0() asm volatile("s_waitcnt vmcnt(0)" ::: "memory")
#define MFMA_(a,b,c) __builtin_amdgcn_mfma_f32_16x16x32_bf16(a, b, c, 0, 0, 0)

__device__ __forceinline__ u16 f2bf(float f) {
  u32 u = __float_as_uint(f);
  u += 0x7FFFu + ((u >> 16) & 1u);   // RNE
  return (u16)(u >> 16);
}

__device__ __forceinline__ void gld16(void* lds, const void* g) {
  __builtin_amdgcn_global_load_lds(
      (__attribute__((address_space(1))) void*)g,
      (__attribute__((address_space(3))) void*)lds, 16, 0, 0);
}

// ---------------- mask decoding (layout-robust) ----------------
__device__ __forceinline__ int detect_layout(const u32* mi) {
  const int lane = threadIdx.x & 63;
  bool all01 = true, allf = true;
  for (int j = 0; j < 8; ++j) {
    u32 w = mi[j * 64 + lane];
    all01 &= (w <= 1u);
    allf  &= (w == 0u || w == 0x3F800000u);
  }
  unsigned long long b01 = __ballot(all01);
  unsigned long long bfl = __ballot(allf);
  if (b01 == ~0ull) return 0;
  if (bfl == ~0ull) return 1;
  return 2;
}

__device__ __forceinline__ bool mask_at(const void* m, int layout, int e, int n) {
  if (layout == 0) return ((const u32*)m)[e * NTOK + n] != 0u;
  if (layout == 1) return ((const float*)m)[e * NTOK + n] != 0.f;
  return ((const unsigned char*)m)[e * NTOK + n] != 0;
}

__device__ __forceinline__ int label_of(const void* m, int layout, int n) {
  for (int e = 0; e < NEXP; ++e)
    if (mask_at(m, layout, e, n)) return e;
  return 0;
}

// ---------------- fused count+scan+fill: deterministic prefix scan ---------
__global__ __launch_bounds__(1024) void k_setup(const void* __restrict__ masks,
                                                int* __restrict__ meta,
                                                int* __restrict__ idx) {
  const int layout = detect_layout((const u32*)masks);
  const int t = threadIdx.x;
  const int base_n = t << 5;           // 32 tokens per thread
  u32 bits = 0; int c0 = 0;
  for (int j = 0; j < 32; ++j) {
    const int l_ = label_of(masks, layout, base_n + j);
    bits |= ((u32)l_) << j;
    c0 += 1 - l_;
  }
  int inc = c0;
#pragma unroll
  for (int d = 1; d < 64; d <<= 1) {
    int v = __shfl_up(inc, d, 64);
    if ((t & 63) >= d) inc += v;
  }
  __shared__ int wsum[16];
  __shared__ int wexc[17];
  const int wv = t >> 6, ln = t & 63;
  if (ln == 63) wsum[wv] = inc;
  __syncthreads();
  if (t == 0) {
    int a = 0;
    for (int w = 0; w < 16; ++w) { wexc[w] = a; a += wsum[w]; }
    wexc[16] = a;
  }
  __syncthreads();
  const int cnt0 = wexc[16];
  int p0 = wexc[wv] + inc - c0;        // exclusive prefix of expert-0 count
  int p1 = cnt0 + base_n - p0;         // cnt0 + (32t - excl0)
  for (int j = 0; j < 32; ++j) {
    const int n = base_n + j;
    if ((bits >> j) & 1u) idx[p1++] = n;
    else                  idx[p0++] = n;
  }
  if (t == 0) { meta[0] = cnt0; meta[1] = NTOK - cnt0; }
}

// ---------------- f32 -> bf16, grid-stride (weights) ----------------
__global__ void k_cvt(const float* __restrict__ in, u16* __restrict__ out, int n4) {
  const int stride = gridDim.x * blockDim.x;
  for (int i = blockIdx.x * blockDim.x + threadIdx.x; i < n4; i += stride) {
    const float4 v = ((const float4*)in)[i];
    ushort4 o;
    o.x = f2bf(v.x); o.y = f2bf(v.y); o.z = f2bf(v.z); o.w = f2bf(v.w);
    ((ushort4*)out)[i] = o;
  }
}

// ---------------- x: f32 -> bf16, GATHERED into expert-sorted order --------
__global__ __launch_bounds__(256) void k_cvtx(const float* __restrict__ x,
                                              const int* __restrict__ idx,
                                              u16* __restrict__ xg) {
  const int r = blockIdx.x;
  const int tok = idx[r];
  const float4 v = ((const float4*)(x + ((size_t)tok << 10)))[threadIdx.x];
  ushort4 o;
  o.x = f2bf(v.x); o.y = f2bf(v.y); o.z = f2bf(v.z); o.w = f2bf(v.w);
  ((ushort4*)(xg + ((size_t)r << 10)))[threadIdx.x] = o;
}

// ============================================================================
// GEMM1 (persistent): h = silu(Xg@W1^T) * (Xg@W3^T), rows pre-gathered.
// 256 blocks, 8 waves, BM=256, BN=128 dual-B, BK=64, 128 KiB LDS.
// B-register-hold: all B frags read ONCE per K-tile at phase (0,0), held in
// 8 bf16x8 regs across MQ -> 24 ds_read_b128/wave/K-tile (was 32).
// ============================================================================

#define ST1A(BUF, HH, P_, KT) {                                        \
    char* _d = (char*)&sA[BUF][(HH) * 8192] + t * 16;                  \
    gld16(_d,        ((HH) ? P_.a2 : P_.a0) + (size_t)(KT) * 64);      \
    gld16(_d + 8192, ((HH) ? P_.a3 : P_.a1) + (size_t)(KT) * 64); }

#define ST1B(BUF, HH, P_, KT) {                                                 \
    gld16((char*)&sB1[BUF][(HH) * 4096] + t * 16,                               \
          ((HH) ? P_.b11 : P_.b10) + (size_t)(KT) * 64);                        \
    gld16((char*)&sB3[BUF][(HH) * 4096] + t * 16,                               \
          ((HH) ? P_.b31 : P_.b30) + (size_t)(KT) * 64); }

#define G1_PH(MQ, NQ, ...) {                                                   \
    if ((MQ) == 0 && (NQ) == 0) {                                              \
      _Pragma("unroll") for (int q_ = 0; q_ < 2; ++q_) {                       \
        b1f0[q_] = *(const bf16x8*)&sB1c[bBase + q_*4096 + kb0];               \
        b1f1[q_] = *(const bf16x8*)&sB1c[bBase + q_*4096 + kb1];               \
        b3f0[q_] = *(const bf16x8*)&sB3c[bBase + q_*4096 + kb0];               \
        b3f1[q_] = *(const bf16x8*)&sB3c[bBase + q_*4096 + kb1];               \
      }                                                                        \
    }                                                                          \
    if ((NQ) == 0) {                                                           \
      _Pragma("unroll") for (int mi = 0; mi < 4; ++mi) {                       \
        af0[mi] = *(const bf16x8*)&sAc[aBase + (MQ)*8192 + mi*1024 + kb0];     \
        af1[mi] = *(const bf16x8*)&sAc[aBase + (MQ)*8192 + mi*1024 + kb1];     \
      }                                                                        \
    }                                                                          \
    __VA_ARGS__                                                                \
    BAR();                                                                     \
    __builtin_amdgcn_s_setprio(1);                                             \
    _Pragma("unroll") for (int mi = 0; mi < 4; ++mi) {                         \
      acc1[MQ][NQ][mi] = MFMA_(af0[mi], b1f0[NQ], acc1[MQ][NQ][mi]);           \
      acc3[MQ][NQ][mi] = MFMA_(af0[mi], b3f0[NQ], acc3[MQ][NQ][mi]);           \
      acc1[MQ][NQ][mi] = MFMA_(af1[mi], b1f1[NQ], acc1[MQ][NQ][mi]);           \
      acc3[MQ][NQ][mi] = MFMA_(af1[mi], b3f1[NQ], acc3[MQ][NQ][mi]);           \
    }                                                                          \
    __builtin_amdgcn_s_setprio(0);                                             \
  }

#define SETUP1(P_, IT) {                                                        \
    int _it = (IT);                                                            \
    int _m  = c + ((_it / NNT1) << 3);                                         \
    P_.nT   = _it % NNT1;                                                      \
    int _e  = _m >= nmt0;                                                      \
    P_.mT   = _e ? _m - nmt0 : _m;                                             \
    P_.cnt  = _e ? cnt1 : cnt0;                                                \
    P_.bas  = _e ? cnt0 : 0;                                                   \
    int _rg;                                                                   \
    _rg = P_.mT*256       + r0; _rg = _rg < P_.cnt ? _rg : P_.cnt-1;           \
    P_.a0 = xg + (size_t)(P_.bas+_rg)*DIM + srcoff;                            \
    _rg = P_.mT*256 +  64 + r0; _rg = _rg < P_.cnt ? _rg : P_.cnt-1;           \
    P_.a1 = xg + (size_t)(P_.bas+_rg)*DIM + srcoff;                            \
    _rg = P_.mT*256 + 128 + r0; _rg = _rg < P_.cnt ? _rg : P_.cnt-1;           \
    P_.a2 = xg + (size_t)(P_.bas+_rg)*DIM + srcoff;                            \
    _rg = P_.mT*256 + 192 + r0; _rg = _rg < P_.cnt ? _rg : P_.cnt-1;           \
    P_.a3 = xg + (size_t)(P_.bas+_rg)*DIM + srcoff;                            \
    size_t _o = ((size_t)_e * HID + (size_t)P_.nT * 128 + r0) * DIM + srcoff;  \
    P_.b10 = w1b + _o; P_.b11 = w1b + _o + (size_t)64 * DIM;                   \
    P_.b30 = w3b + _o; P_.b31 = w3b + _o + (size_t)64 * DIM; }

__global__ __launch_bounds__(512, 2) void k_gemm1(
    const u16* __restrict__ xg, const u16* __restrict__ w1b,
    const u16* __restrict__ w3b, const int* __restrict__ meta,
    u16* __restrict__ h)
{
  const int cnt0 = meta[0], cnt1 = meta[1];
  const int nmt0 = (cnt0 + 255) >> 8;
  const int nmt  = nmt0 + ((cnt1 + 255) >> 8);
  const int c = blockIdx.x & 7, q = blockIdx.x >> 3;
  const int mcnt  = (nmt > c) ? (((nmt - 1 - c) >> 3) + 1) : 0;
  const int items = mcnt * NNT1;
  int i = q;
  if (i >= items) return;

  __shared__ __attribute__((aligned(16))) u16 sA [2][256 * 64];
  __shared__ __attribute__((aligned(16))) u16 sB1[2][128 * 64];
  __shared__ __attribute__((aligned(16))) u16 sB3[2][128 * 64];

  const int t = threadIdx.x;
  const int srcoff = ((t & 7) ^ ((t >> 3) & 7)) * 8;   // pre-swizzled src (u16)
  const int r0 = t >> 3;
  const int wid = t >> 6, l = t & 63;
  const int wr = wid >> 2, wc = wid & 3;
  const int l15 = l & 15, lk = l >> 4, l7 = l & 7;
  const int kb0 = ((0 + lk) ^ l7) * 8;
  const int kb1 = ((4 + lk) ^ l7) * 8;
  const int aBase = (wr * 64 + l15) * 64;
  const int bBase = (wc * 16 + l15) * 64;

  struct P { const u16 *a0,*a1,*a2,*a3,*b10,*b11,*b30,*b31; int mT,cnt,bas,nT; };
  P cur, nxt;
  SETUP1(cur, i)
  bool hasN = (i + 32) < items;
  if (hasN) { SETUP1(nxt, i + 32) } else { nxt = cur; }

  f32x4 acc1[2][2][4] = {};
  f32x4 acc3[2][2][4] = {};
  bf16x8 af0[4], af1[4];
  bf16x8 b1f0[2], b1f1[2], b3f0[2], b3f1[2];

  ST1A(0, 0, cur, 0) ST1A(0, 1, cur, 0) ST1B(0, 0, cur, 0) ST1B(0, 1, cur, 0)
  ST1A(1, 0, cur, 1) ST1A(1, 1, cur, 1) ST1B(1, 0, cur, 1)
  WAIT6();
  BAR();

  for (;;) {
#pragma unroll 2
    for (int k = 0; k < NK1 - 2; ++k) {
      const u16* sAc  = &sA [k & 1][0];
      const u16* sB1c = &sB1[k & 1][0];
      const u16* sB3c = &sB3[k & 1][0];
      G1_PH(0, 0, ST1B((k & 1) ^ 1, 1, cur, k + 1))
      BAR();
      G1_PH(0, 1, ST1A(k & 1, 0, cur, k + 2))
      BAR();
      G1_PH(1, 0, )
      BAR();
      G1_PH(1, 1, ST1A(k & 1, 1, cur, k + 2) ST1B(k & 1, 0, cur, k + 2))
      WAIT6();
      BAR();
    }
    {   // k = NK1-2: prefetch slots -> next item's step 0
      const u16* sAc  = &sA [0][0];
      const u16* sB1c = &sB1[0][0];
      const u16* sB3c = &sB3[0][0];
      G1_PH(0, 0, ST1B(1, 1, cur, 15))
      BAR();
      G1_PH(0, 1, if (hasN) ST1A(0, 0, nxt, 0))
      BAR();
      G1_PH(1, 0, )
      BAR();
      G1_PH(1, 1, if (hasN) { ST1A(0, 1, nxt, 0) ST1B(0, 0, nxt, 0) })
      if (hasN) WAIT6(); else WAIT0();
      BAR();
    }
    {   // k = NK1-1: prefetch slots -> next item's steps 0/1
      const u16* sAc  = &sA [1][0];
      const u16* sB1c = &sB1[1][0];
      const u16* sB3c = &sB3[1][0];
      G1_PH(0, 0, if (hasN) ST1B(0, 1, nxt, 0))
      BAR();
      G1_PH(0, 1, if (hasN) ST1A(1, 0, nxt, 1))
      BAR();
      G1_PH(1, 0, )
      BAR();
      G1_PH(1, 1, if (hasN) { ST1A(1, 1, nxt, 1) ST1B(1, 0, nxt, 1) })
      if (hasN) WAIT6();
      BAR();
    }

    // epilogue: h = silu(acc1) * acc3 (overlaps next item's in-flight stages)
#pragma unroll
    for (int mq = 0; mq < 2; ++mq)
#pragma unroll
      for (int mi = 0; mi < 4; ++mi)
#pragma unroll
        for (int r = 0; r < 4; ++r) {
          const int lrow = mq * 128 + wr * 64 + mi * 16 + lk * 4 + r;
          const int rg = cur.mT * 256 + lrow;
          if (rg < cur.cnt) {
            u16* hrow = h + (size_t)(cur.bas + rg) * HID + cur.nT * 128 + wc * 16 + l15;
#pragma unroll
            for (int nq = 0; nq < 2; ++nq) {
              const float a = acc1[mq][nq][mi][r];
              const float b = acc3[mq][nq][mi][r];
              hrow[nq * 64] = f2bf((a / (1.f + __expf(-a))) * b);
            }
          }
        }

    if (!hasN) break;
    cur = nxt;
    i += 32;
    hasN = (i + 32) < items;
    if (hasN) SETUP1(nxt, i + 32)
#pragma unroll
    for (int a_ = 0; a_ < 2; ++a_)
#pragma unroll
      for (int b_ = 0; b_ < 2; ++b_)
#pragma unroll
        for (int m_ = 0; m_ < 4; ++m_) {
          acc1[a_][b_][m_] = (f32x4){0.f, 0.f, 0.f, 0.f};
          acc3[a_][b_][m_] = (f32x4){0.f, 0.f, 0.f, 0.f};
        }
  }
}

// ============================================================================
// GEMM2 (persistent): O = H @ W2^T, scatter f32 rows. Same B-register-hold.
// ============================================================================

#define ST2A(BUF, HH, P_, KT) {                                        \
    char* _d = (char*)&sA[BUF][(HH) * 8192] + t * 16;                  \
    gld16(_d,        ((HH) ? P_.a2 : P_.a0) + (size_t)(KT) * 64);      \
    gld16(_d + 8192, ((HH) ? P_.a3 : P_.a1) + (size_t)(KT) * 64); }

#define ST2B(BUF, HH, P_, KT) {                                        \
    char* _d = (char*)&sB[BUF][(HH) * 8192] + t * 16;                  \
    gld16(_d,        ((HH) ? P_.b2 : P_.b0) + (size_t)(KT) * 64);      \
    gld16(_d + 8192, ((HH) ? P_.b3 : P_.b1) + (size_t)(KT) * 64); }

#define G2_PH(MQ, NQ, ...) {                                                   \
    if ((MQ) == 0 && (NQ) == 0) {                                              \
      _Pragma("unroll") for (int q_ = 0; q_ < 2; ++q_)                         \
        _Pragma("unroll") for (int ni = 0; ni < 2; ++ni) {                     \
          bf0[q_][ni] = *(const bf16x8*)&sBc[bBase + q_*8192 + ni*1024 + kb0]; \
          bf1[q_][ni] = *(const bf16x8*)&sBc[bBase + q_*8192 + ni*1024 + kb1]; \
        }                                                                      \
    }                                                                          \
    if ((NQ) == 0) {                                                           \
      _Pragma("unroll") for (int mi = 0; mi < 4; ++mi) {                       \
        af0[mi] = *(const bf16x8*)&sAc[aBase + (MQ)*8192 + mi*1024 + kb0];     \
        af1[mi] = *(const bf16x8*)&sAc[aBase + (MQ)*8192 + mi*1024 + kb1];     \
      }                                                                        \
    }                                                                          \
    __VA_ARGS__                                                                \
    BAR();                                                                     \
    __builtin_amdgcn_s_setprio(1);                                             \
    _Pragma("unroll") for (int mi = 0; mi < 4; ++mi)                           \
      _Pragma("unroll") for (int ni = 0; ni < 2; ++ni) {                       \
        acc[MQ][NQ][mi][ni] = MFMA_(af0[mi], bf0[NQ][ni], acc[MQ][NQ][mi][ni]);\
        acc[MQ][NQ][mi][ni] = MFMA_(af1[mi], bf1[NQ][ni], acc[MQ][NQ][mi][ni]);\
      }                                                                        \
    __builtin_amdgcn_s_setprio(0);                                             \
  }

#define SETUP2(P_, IT) {                                                        \
    int _it = (IT);                                                            \
    int _m  = c + ((_it >> 2) << 3);                                           \
    P_.nT   = _it & 3;                                                         \
    int _e  = _m >= nmt0;                                                      \
    P_.mT   = _e ? _m - nmt0 : _m;                                             \
    P_.cnt  = _e ? cnt1 : cnt0;                                                \
    P_.bas  = _e ? cnt0 : 0;                                                   \
    int _rg;                                                                   \
    _rg = P_.mT*256       + r0; _rg = _rg < P_.cnt ? _rg : P_.cnt-1;           \
    P_.a0 = hbuf + (size_t)(P_.bas+_rg)*HID + srcoff;                          \
    _rg = P_.mT*256 +  64 + r0; _rg = _rg < P_.cnt ? _rg : P_.cnt-1;           \
    P_.a1 = hbuf + (size_t)(P_.bas+_rg)*HID + srcoff;                          \
    _rg = P_.mT*256 + 128 + r0; _rg = _rg < P_.cnt ? _rg : P_.cnt-1;           \
    P_.a2 = hbuf + (size_t)(P_.bas+_rg)*HID + srcoff;                          \
    _rg = P_.mT*256 + 192 + r0; _rg = _rg < P_.cnt ? _rg : P_.cnt-1;           \
    P_.a3 = hbuf + (size_t)(P_.bas+_rg)*HID + srcoff;                          \
    size_t _wb = ((size_t)_e * DIM + (size_t)P_.nT * 256 + r0) * HID + srcoff; \
    P_.b0 = w2b + _wb;                                                         \
    P_.b1 = w2b + _wb + (size_t) 64 * HID;                                     \
    P_.b2 = w2b + _wb + (size_t)128 * HID;                                     \
    P_.b3 = w2b + _wb + (size_t)192 * HID; }

__global__ __launch_bounds__(512, 2) void k_gemm2(
    const u16* __restrict__ hbuf, const u16* __restrict__ w2b,
    const int* __restrict__ meta, const int* __restrict__ idx,
    float* __restrict__ out)
{
  const int cnt0 = meta[0], cnt1 = meta[1];
  const int nmt0 = (cnt0 + 255) >> 8;
  const int nmt  = nmt0 + ((cnt1 + 255) >> 8);
  const int c = blockIdx.x & 7, q = blockIdx.x >> 3;
  const int mcnt  = (nmt > c) ? (((nmt - 1 - c) >> 3) + 1) : 0;
  const int items = mcnt * NNT2;
  int i = q;
  if (i >= items) return;

  __shared__ __attribute__((aligned(16))) u16 sA[2][256 * 64];
  __shared__ __attribute__((aligned(16))) u16 sB[2][256 * 64];

  const int t = threadIdx.x;
  const int srcoff = ((t & 7) ^ ((t >> 3) & 7)) * 8;
  const int r0 = t >> 3;
  const int wid = t >> 6, l = t & 63;
  const int wr = wid >> 2, wc = wid & 3;
  const int l15 = l & 15, lk = l >> 4, l7 = l & 7;
  const int kb0 = ((0 + lk) ^ l7) * 8;
  const int kb1 = ((4 + lk) ^ l7) * 8;
  const int aBase = (wr * 64 + l15) * 64;
  const int bBase = (wc * 32 + l15) * 64;

  struct P { const u16 *a0,*a1,*a2,*a3,*b0,*b1,*b2,*b3; int mT,cnt,bas,nT; };
  P cur, nxt;
  SETUP2(cur, i)
  bool hasN = (i + 32) < items;
  if (hasN) { SETUP2(nxt, i + 32) } else { nxt = cur; }

  f32x4 acc[2][2][4][2] = {};
  bf16x8 af0[4], af1[4], bf0[2][2], bf1[2][2];

  ST2A(0, 0, cur, 0) ST2A(0, 1, cur, 0) ST2B(0, 0, cur, 0) ST2B(0, 1, cur, 0)
  ST2A(1, 0, cur, 1) ST2A(1, 1, cur, 1) ST2B(1, 0, cur, 1)
  WAIT6();
  BAR();

  for (;;) {
#pragma unroll 2
    for (int k = 0; k < NK2 - 2; ++k) {
      const u16* sAc = &sA[k & 1][0];
      const u16* sBc = &sB[k & 1][0];
      G2_PH(0, 0, ST2B((k & 1) ^ 1, 1, cur, k + 1))
      BAR();
      G2_PH(0, 1, ST2A(k & 1, 0, cur, k + 2))
      BAR();
      G2_PH(1, 0, )
      BAR();
      G2_PH(1, 1, ST2A(k & 1, 1, cur, k + 2) ST2B(k & 1, 0, cur, k + 2))
      WAIT6();
      BAR();
    }
    {   // k = NK2-2
      const u16* sAc = &sA[0][0];
      const u16* sBc = &sB[0][0];
      G2_PH(0, 0, ST2B(1, 1, cur, NK2 - 1))
      BAR();
      G2_PH(0, 1, if (hasN) ST2A(0, 0, nxt, 0))
      BAR();
      G2_PH(1, 0, )
      BAR();
      G2_PH(1, 1, if (hasN) { ST2A(0, 1, nxt, 0) ST2B(0, 0, nxt, 0) })
      if (hasN) WAIT6(); else WAIT0();
      BAR();
    }
    {   // k = NK2-1
      const u16* sAc = &sA[1][0];
      const u16* sBc = &sB[1][0];
      G2_PH(0, 0, if (hasN) ST2B(0, 1, nxt, 0))
      BAR();
      G2_PH(0, 1, if (hasN) ST2A(1, 0, nxt, 1))
      BAR();
      G2_PH(1, 0, )
      BAR();
      G2_PH(1, 1, if (hasN) { ST2A(1, 1, nxt, 1) ST2B(1, 0, nxt, 1) })
      if (hasN) WAIT6();
      BAR();
    }

#pragma unroll
    for (int mq = 0; mq < 2; ++mq)
#pragma unroll
      for (int mi = 0; mi < 4; ++mi)
#pragma unroll
        for (int r = 0; r < 4; ++r) {
          const int lrow = mq * 128 + wr * 64 + mi * 16 + lk * 4 + r;
          const int rg = cur.mT * 256 + lrow;
          if (rg < cur.cnt) {
            const int tok = idx[cur.bas + rg];
            float* orow = out + (size_t)tok * DIM + cur.nT * 256 + wc * 32 + l15;
#pragma unroll
            for (int nq = 0; nq < 2; ++nq)
#pragma unroll
              for (int ni = 0; ni < 2; ++ni)
                orow[nq * 128 + ni * 16] = acc[mq][nq][mi][ni][r];
          }
        }

    if (!hasN) break;
    cur = nxt;
    i += 32;
    hasN = (i + 32) < items;
    if (hasN) SETUP2(nxt, i + 32)
#pragma unroll
    for (int a_ = 0; a_ < 2; ++a_)
#pragma unroll
      for (int b_ = 0; b_ < 2; ++b_)
#pragma unroll
        for (int m_ = 0; m_ < 4; ++m_)
#pragma unroll
          for (int n_ = 0; n_ < 2; ++n_)
            acc[a_][b_][m_][n_] = (f32x4){0.f, 0.f, 0.f, 0.f};
  }
}

// ---------------- RMSNorm: 4 rows/block, one row per wave (no barriers) ----
__global__ __launch_bounds__(256) void k_rms(
    float* __restrict__ out, const float* __restrict__ nw,
    const int* __restrict__ meta, const int* __restrict__ idx)
{
  const int wv = threadIdx.x >> 6, ln = threadIdx.x & 63;
  const int r = blockIdx.x * 4 + wv;
  const int e = (r >= meta[0]) ? 1 : 0;
  const int tok = idx[r];
  float* row = out + (size_t)tok * DIM;
  const float* g = nw + (size_t)e * DIM;

  float4 v[4];
  float ss = 0.f;
#pragma unroll
  for (int p = 0; p < 4; ++p) {
    v[p] = ((const float4*)row)[p * 64 + ln];
    ss += v[p].x * v[p].x + v[p].y * v[p].y + v[p].z * v[p].z + v[p].w * v[p].w;
  }
#pragma unroll
  for (int off = 32; off; off >>= 1) ss += __shfl_xor(ss, off, 64);
  const float sc = rsqrtf(ss * (1.0f / DIM) + RMS_EPS);
#pragma unroll
  for (int p = 0; p < 4; ++p) {
    const float4 gg = ((const float4*)g)[p * 64 + ln];
    v[p].x *= sc * gg.x; v[p].y *= sc * gg.y;
    v[p].z *= sc * gg.z; v[p].w *= sc * gg.w;
    ((float4*)row)[p * 64 + ln] = v[p];
  }
}

// ---------------- launch ----------------
extern "C" void kernel_launch(void* const* d_in, const int* in_sizes, int n_in,
                              void* d_out, int out_size, void* d_ws, size_t ws_size,
                              hipStream_t stream)
{
  const float* x     = (const float*)d_in[0];
  const void*  masks = d_in[1];
  const float* w1    = (const float*)d_in[2];
  const float* w3    = (const float*)d_in[3];
  const float* w2    = (const float*)d_in[4];
  const float* nw    = (const float*)d_in[5];
  float* out = (float*)d_out;

  char* ws = (char*)d_ws;
  constexpr size_t OFF_IDX = 256;
  constexpr size_t OFF_XB  = OFF_IDX + (size_t)NTOK * 4;
  constexpr size_t OFF_W1B = OFF_XB + (size_t)NTOK * DIM * 2;
  constexpr size_t SZ_W    = (size_t)NEXP * HID * DIM * 2;
  constexpr size_t OFF_W3B = OFF_W1B + SZ_W;
  constexpr size_t OFF_W2B = OFF_W3B + SZ_W;
  constexpr size_t OFF_H   = OFF_W2B + SZ_W;

  int* meta = (int*)ws;
  int* idx  = (int*)(ws + OFF_IDX);
  u16* xg   = (u16*)(ws + OFF_XB);
  u16* w1b  = (u16*)(ws + OFF_W1B);
  u16* w3b  = (u16*)(ws + OFF_W3B);
  u16* w2b  = (u16*)(ws + OFF_W2B);
  u16* h    = (u16*)(ws + OFF_H);

  k_setup<<<1, 1024, 0, stream>>>(masks, meta, idx);

  const int wn4 = NEXP * HID * DIM / 4;
  k_cvt<<<2048, 256, 0, stream>>>(w1, w1b, wn4);
  k_cvt<<<2048, 256, 0, stream>>>(w3, w3b, wn4);
  k_cvt<<<2048, 256, 0, stream>>>(w2, w2b, wn4);
  k_cvtx<<<NTOK, 256, 0, stream>>>(x, idx, xg);

  k_gemm1<<<256, 512, 0, stream>>>(xg, w1b, w3b, meta, h);
  k_gemm2<<<256, 512, 0, stream>>>(h, w2b, meta, idx, out);
  k_rms<<<NTOK / 4, 256, 0, stream>>>(out, nw, meta, idx);
}